// Round 14
// baseline (868.237 us; speedup 1.0000x reference)
//
#include <hip/hip_runtime.h>
#include <stdint.h>

#define T_TOK 4096
#define HDIM  2048
#define SEQ   2048
#define NHQ   16
#define NKVH  4
#define DH    128
#define NE    16
#define CCAP  1024
#define FF    768
#define EPSF  1e-6f

typedef __attribute__((ext_vector_type(4))) float          f32x4;
typedef __attribute__((ext_vector_type(8))) _Float16       f16x8;
typedef __attribute__((ext_vector_type(4))) unsigned short u16x4;
typedef __attribute__((ext_vector_type(8))) unsigned short u16x8;

__device__ __forceinline__ unsigned short f2h(float f){ return __builtin_bit_cast(unsigned short, (_Float16)f); }
__device__ __forceinline__ float h2f(unsigned short u){ return (float)__builtin_bit_cast(_Float16, u); }
__device__ __forceinline__ void split2(float x, unsigned short& hi, unsigned short& lo){
  unsigned short h = f2h(x);
  hi = h; lo = f2h((x - h2f(h)) * 4096.f);
}
__device__ __forceinline__ void gl_lds16(const void* g, void* l){
  __builtin_amdgcn_global_load_lds((const __attribute__((address_space(1))) unsigned int*)g,
                                   (__attribute__((address_space(3))) unsigned int*)l, 16, 0, 0);
}
// R7: B-side LDS swizzle for the on-the-fly f32 path (MoE GEMMs only now).
__device__ __forceinline__ int bswz(int row){ return ((row & 7) ^ ((row >> 3) & 7)) << 3; }

// ---------------- residual add + RMSNorm -> split f16 h ----------------
__global__ __launch_bounds__(256) void k_addnorm(
    const float* __restrict__ hs, const float* __restrict__ rs, const float* __restrict__ w,
    float* __restrict__ resid, unsigned short* __restrict__ hhi, unsigned short* __restrict__ hlo)
{
  int t = blockIdx.x, tid = threadIdx.x;
  size_t off = (size_t)t * HDIM;
  float4 a0 = ((const float4*)(hs+off))[tid];
  float4 b0 = ((const float4*)(rs+off))[tid];
  float4 a1 = ((const float4*)(hs+off))[tid+256];
  float4 b1 = ((const float4*)(rs+off))[tid+256];
  float4 s0 = make_float4(a0.x+b0.x, a0.y+b0.y, a0.z+b0.z, a0.w+b0.w);
  float4 s1 = make_float4(a1.x+b1.x, a1.y+b1.y, a1.z+b1.z, a1.w+b1.w);
  float ssq = s0.x*s0.x+s0.y*s0.y+s0.z*s0.z+s0.w*s0.w
            + s1.x*s1.x+s1.y*s1.y+s1.z*s1.z+s1.w*s1.w;
  #pragma unroll
  for (int sh=1; sh<64; sh<<=1) ssq += __shfl_xor(ssq, sh);
  __shared__ float red[4];
  if ((tid & 63) == 0) red[tid>>6] = ssq;
  __syncthreads();
  float tot = red[0]+red[1]+red[2]+red[3];
  float r = 1.f / sqrtf(tot * (1.f/HDIM) + EPSF);
  ((float4*)(resid+off))[tid]     = s0;
  ((float4*)(resid+off))[tid+256] = s1;
  float4 w0 = ((const float4*)w)[tid];
  float4 w1 = ((const float4*)w)[tid+256];
  u16x4 hv, lv; unsigned short ta, tb;
  split2(s0.x*r*w0.x, ta, tb); hv.x=ta; lv.x=tb;
  split2(s0.y*r*w0.y, ta, tb); hv.y=ta; lv.y=tb;
  split2(s0.z*r*w0.z, ta, tb); hv.z=ta; lv.z=tb;
  split2(s0.w*r*w0.w, ta, tb); hv.w=ta; lv.w=tb;
  ((u16x4*)(hhi+off))[tid] = hv; ((u16x4*)(hlo+off))[tid] = lv;
  split2(s1.x*r*w1.x, ta, tb); hv.x=ta; lv.x=tb;
  split2(s1.y*r*w1.y, ta, tb); hv.y=ta; lv.y=tb;
  split2(s1.z*r*w1.z, ta, tb); hv.z=ta; lv.z=tb;
  split2(s1.w*r*w1.w, ta, tb); hv.w=ta; lv.w=tb;
  ((u16x4*)(hhi+off))[tid+256] = hv; ((u16x4*)(hlo+off))[tid+256] = lv;
}

// ---------------- RoPE cos/sin table (match np f32 powf via f64) ----------------
__global__ void k_cstab(const int* __restrict__ pos, float* __restrict__ cs)
{
  int i = blockIdx.x*256 + threadIdx.x;
  if (i >= SEQ*64) return;
  int s = i >> 6, f = i & 63;
  float pw  = (float)exp((double)f * 13.815510557964274 / 64.0); // 1e6^(f/64), CR to f32
  float inv = 1.0f / pw;                                          // two roundings, like reference
  float ang = (float)pos[s] * inv;
  float sv, cv;
  sincosf(ang, &sv, &cv);
  ((float2*)cs)[i] = make_float2(cv, sv);
}

// ---------------- per-head RMSNorm + RoPE (4 heads/block) ----------------
__global__ __launch_bounds__(256) void k_normrope(
    unsigned short* __restrict__ qh, unsigned short* __restrict__ ql,
    unsigned short* __restrict__ kh, unsigned short* __restrict__ kl,
    const float* __restrict__ qnw, const float* __restrict__ knw,
    const float* __restrict__ cs)
{
  int t = blockIdx.x, head = blockIdx.y*4 + (threadIdx.x>>6), lane = threadIdx.x & 63;
  int s = t & (SEQ-1);
  unsigned short *dh, *dl; const float* wn; float scale; size_t off;
  if (head < NHQ){ off = ((size_t)t*NHQ + head)*DH; dh = qh+off; dl = ql+off; wn = qnw; scale = 0.08838834764831845f; }
  else           { off = ((size_t)t*NKVH + (head-NHQ))*DH; dh = kh+off; dl = kl+off; wn = knw; scale = 1.f; }
  float x1 = h2f(dh[lane])    + h2f(dl[lane])   *(1.f/4096.f);
  float x2 = h2f(dh[lane+64]) + h2f(dl[lane+64])*(1.f/4096.f);
  float ssq = x1*x1 + x2*x2;
  #pragma unroll
  for (int sh=1; sh<64; sh<<=1) ssq += __shfl_xor(ssq, sh);
  float r = 1.f / sqrtf(ssq * (1.f/DH) + EPSF);
  float y1 = x1*r*wn[lane], y2 = x2*r*wn[lane+64];
  float2 csp = ((const float2*)cs)[s*64 + lane];
  float o1 = (y1*csp.x - y2*csp.y) * scale;
  float o2 = (y2*csp.x + y1*csp.y) * scale;
  unsigned short a, b;
  split2(o1, a, b); dh[lane]    = a; dl[lane]    = b;
  split2(o2, a, b); dh[lane+64] = a; dl[lane+64] = b;
}

// ---------------- R13: one-time weight split+transpose ----------------
// W [Kd][Ncols] f32  ->  Whi/Wlo [Ncols][Kd] u16 (transposed, split2 planes).
__global__ __launch_bounds__(256) void k_wsplit(
    const float* __restrict__ W, int Kd, int Ncols,
    unsigned short* __restrict__ Whi, unsigned short* __restrict__ Wlo)
{
  int k0 = blockIdx.x*64, n0 = blockIdx.y*64;
  __shared__ float T[64][65];
  int tid = threadIdx.x;
  int tr = tid >> 4;
  int tc = (tid & 15) * 4;
  #pragma unroll
  for (int i=0;i<4;i++){
    int k = tr + i*16;
    float4 v = *(const float4*)(W + (size_t)(k0 + k)*Ncols + n0 + tc);
    T[k][tc+0]=v.x; T[k][tc+1]=v.y; T[k][tc+2]=v.z; T[k][tc+3]=v.w;
  }
  __syncthreads();
  int n  = tid >> 2;
  int kc = (tid & 3) * 16;
  u16x8 hv0, lv0, hv1, lv1;
  #pragma unroll
  for (int j=0;j<8;j++){
    unsigned short hi, lo; split2(T[kc+j][n], hi, lo);
    hv0[j]=hi; lv0[j]=lo;
  }
  #pragma unroll
  for (int j=0;j<8;j++){
    unsigned short hi, lo; split2(T[kc+8+j][n], hi, lo);
    hv1[j]=hi; lv1[j]=lo;
  }
  size_t ob = (size_t)(n0 + n)*Kd + k0 + kc;
  *(u16x8*)(Whi + ob)     = hv0;
  *(u16x8*)(Whi + ob + 8) = hv1;
  *(u16x8*)(Wlo + ob)     = lv0;
  *(u16x8*)(Wlo + ob + 8) = lv1;
}

// ---------------- R19: merged QKV weight split (one launch) ----------------
// grid (32, 48): y<32 -> wq (2048 cols), 32..39 -> wk (512), 40..47 -> wv (512).
// Output rows offset by 0 / 2048 / 2560 in the combined [3072][2048] planes.
__global__ __launch_bounds__(256) void k_wsplit3(
    const float* __restrict__ wq, const float* __restrict__ wk, const float* __restrict__ wv,
    unsigned short* __restrict__ Whi, unsigned short* __restrict__ Wlo)
{
  const int Kd = HDIM;
  int k0 = blockIdx.x*64, ny = blockIdx.y;
  const float* W; int Ncols, n0, noff;
  if (ny < 32){ W = wq; Ncols = 2048; n0 = ny*64;      noff = 0;    }
  else if (ny < 40){ W = wk; Ncols = 512; n0 = (ny-32)*64; noff = 2048; }
  else { W = wv; Ncols = 512; n0 = (ny-40)*64; noff = 2560; }
  __shared__ float T[64][65];
  int tid = threadIdx.x;
  int tr = tid >> 4;
  int tc = (tid & 15) * 4;
  #pragma unroll
  for (int i=0;i<4;i++){
    int k = tr + i*16;
    float4 v = *(const float4*)(W + (size_t)(k0 + k)*Ncols + n0 + tc);
    T[k][tc+0]=v.x; T[k][tc+1]=v.y; T[k][tc+2]=v.z; T[k][tc+3]=v.w;
  }
  __syncthreads();
  int n  = tid >> 2;
  int kc = (tid & 3) * 16;
  u16x8 hv0, lv0, hv1, lv1;
  #pragma unroll
  for (int j=0;j<8;j++){
    unsigned short hi, lo; split2(T[kc+j][n], hi, lo);
    hv0[j]=hi; lv0[j]=lo;
  }
  #pragma unroll
  for (int j=0;j<8;j++){
    unsigned short hi, lo; split2(T[kc+8+j][n], hi, lo);
    hv1[j]=hi; lv1[j]=lo;
  }
  size_t ob = (size_t)(noff + n0 + n)*Kd + k0 + kc;
  *(u16x8*)(Whi + ob)     = hv0;
  *(u16x8*)(Whi + ob + 8) = hv1;
  *(u16x8*)(Wlo + ob)     = lv0;
  *(u16x8*)(Wlo + ob + 8) = lv1;
}

// ---------------- fused QKV GEMM (split-f16 3-pass, pre-split B) ----------------
// grid (32, 24): bn2<16 -> Q, 16..19 -> K, 20..23 -> V
__global__ __launch_bounds__(256,2) void k_gemm_qkv(
    const unsigned short* __restrict__ Ahi, const unsigned short* __restrict__ Alo,
    const unsigned short* __restrict__ Whi, const unsigned short* __restrict__ Wlo,
    unsigned short* __restrict__ qh, unsigned short* __restrict__ ql,
    unsigned short* __restrict__ kh, unsigned short* __restrict__ kl,
    unsigned short* __restrict__ vh, unsigned short* __restrict__ vl)
{
  const int Kd = HDIM;
  int bm = blockIdx.x, bn2 = blockIdx.y;
  int bn, N, noff; unsigned short *Ch, *Cl;
  if (bn2 < 16){ bn = bn2;      N = 2048; noff = 0;    Ch = qh; Cl = ql; }
  else if (bn2 < 20){ bn = bn2-16; N = 512; noff = 2048; Ch = kh; Cl = kl; }
  else { bn = bn2-20; N = 512; noff = 2560; Ch = vh; Cl = vl; }

  __shared__ unsigned short As[2][8192];
  __shared__ unsigned short Bs[2][8192];

  int tid = threadIdx.x, lane = tid & 63, w = tid >> 6;
  int wr = w >> 1, wc = w & 1;

  size_t arow_g[4], brow_g[4];
  int lb_[4];
  #pragma unroll
  for (int i=0;i<4;i++){
    int ob = w*4096 + i*1024 + lane*16;
    int row = ob >> 7;
    int colB = ob & 127;
    int scolB = colB ^ ((row & 7) << 4);
    arow_g[i] = (size_t)(bm*128 + row) * Kd + (scolB >> 1);
    brow_g[i] = (size_t)(noff + bn*128 + row) * Kd + (scolB >> 1);
    lb_[i] = (w*4096 + i*1024) >> 1;
  }

  f32x4 accA[4][4] = {};
  f32x4 accB[4][4] = {};

  for (int kt = 0; kt < Kd/64; kt++){
    #pragma unroll
    for (int i=0;i<4;i++){
      gl_lds16(Ahi + arow_g[i] + kt*64, (void*)&As[0][lb_[i]]);
      gl_lds16(Alo + arow_g[i] + kt*64, (void*)&As[1][lb_[i]]);
      gl_lds16(Whi + brow_g[i] + kt*64, (void*)&Bs[0][lb_[i]]);
      gl_lds16(Wlo + brow_g[i] + kt*64, (void*)&Bs[1][lb_[i]]);
    }
    __syncthreads();
    #pragma unroll
    for (int kk=0; kk<2; kk++){
      f16x8 ah[4], al[4], bh[4], bl[4];
      #pragma unroll
      for (int m=0;m<4;m++){
        int row = wr*64 + m*16 + (lane & 15);
        int ci = (kk*32 + ((lane>>4)<<3)) ^ ((row & 7) << 3);
        ah[m] = *(const f16x8*)&As[0][row*64 + ci];
        al[m] = *(const f16x8*)&As[1][row*64 + ci];
      }
      #pragma unroll
      for (int n=0;n<4;n++){
        int row = wc*64 + n*16 + (lane & 15);
        int ci = (kk*32 + ((lane>>4)<<3)) ^ ((row & 7) << 3);
        bh[n] = *(const f16x8*)&Bs[0][row*64 + ci];
        bl[n] = *(const f16x8*)&Bs[1][row*64 + ci];
      }
      #pragma unroll
      for (int m=0;m<4;m++)
        #pragma unroll
        for (int n=0;n<4;n++){
          accA[m][n] = __builtin_amdgcn_mfma_f32_16x16x32_f16(ah[m], bh[n], accA[m][n], 0,0,0);
          accB[m][n] = __builtin_amdgcn_mfma_f32_16x16x32_f16(ah[m], bl[n], accB[m][n], 0,0,0);
          accB[m][n] = __builtin_amdgcn_mfma_f32_16x16x32_f16(al[m], bh[n], accB[m][n], 0,0,0);
        }
    }
    __syncthreads();
  }
  int r0 = (lane >> 4) << 2, c0 = lane & 15;
  #pragma unroll
  for (int m=0;m<4;m++){
    int grow0 = bm*128 + wr*64 + m*16 + r0;
    #pragma unroll
    for (int n=0;n<4;n++){
      int gcol = bn*128 + wc*64 + n*16 + c0;
      #pragma unroll
      for (int j=0;j<4;j++){
        float v = accA[m][n][j] + accB[m][n][j] * (1.f/4096.f);
        int grow = grow0 + j;
        unsigned short hi, lo; split2(v, hi, lo);
        Ch[(size_t)grow*N + gcol] = hi;
        Cl[(size_t)grow*N + gcol] = lo;
      }
    }
  }
}

// ---------------- O-proj GEMM (split-f16 3-pass, pre-split B, single-buffer) ----------------
// R19: chunked XCD remap — each XCD owns an 8bm x 8bn chunk so both A- and
// B-panels localize (bijective: id = xcd + 8*r, r enumerates the 8x8 chunk).
__global__ __launch_bounds__(256,2) void k_gemm_o(
    const unsigned short* __restrict__ Ahi, const unsigned short* __restrict__ Alo,
    const unsigned short* __restrict__ Bhi, const unsigned short* __restrict__ Blo,
    float* __restrict__ C1)
{
  const int Kd = HDIM, N = 2048;
  int id = blockIdx.x + 32*blockIdx.y;
  int xcd = id & 7, rr = id >> 3;
  int bm = ((xcd & 3) << 3) + (rr & 7);
  int bn = ((xcd >> 2) << 3) + (rr >> 3);

  __shared__ unsigned short As[2][8192];
  __shared__ unsigned short Bs[2][8192];

  int tid = threadIdx.x, lane = tid & 63, w = tid >> 6;
  int wr = w >> 1, wc = w & 1;

  size_t arow_g[4], brow_g[4];
  int lb_[4];
  #pragma unroll
  for (int i=0;i<4;i++){
    int ob = w*4096 + i*1024 + lane*16;
    int row = ob >> 7;
    int colB = ob & 127;
    int scolB = colB ^ ((row & 7) << 4);
    arow_g[i] = (size_t)(bm*128 + row) * Kd + (scolB >> 1);
    brow_g[i] = (size_t)(bn*128 + row) * Kd + (scolB >> 1);
    lb_[i] = (w*4096 + i*1024) >> 1;
  }

  f32x4 accA[4][4] = {};
  f32x4 accB[4][4] = {};

  for (int kt = 0; kt < Kd/64; kt++){
    #pragma unroll
    for (int i=0;i<4;i++){
      gl_lds16(Ahi + arow_g[i] + kt*64, (void*)&As[0][lb_[i]]);
      gl_lds16(Alo + arow_g[i] + kt*64, (void*)&As[1][lb_[i]]);
      gl_lds16(Bhi + brow_g[i] + kt*64, (void*)&Bs[0][lb_[i]]);
      gl_lds16(Blo + brow_g[i] + kt*64, (void*)&Bs[1][lb_[i]]);
    }
    __syncthreads();
    #pragma unroll
    for (int kk=0; kk<2; kk++){
      f16x8 ah[4], al[4], bh[4], bl[4];
      #pragma unroll
      for (int m=0;m<4;m++){
        int row = wr*64 + m*16 + (lane & 15);
        int ci = (kk*32 + ((lane>>4)<<3)) ^ ((row & 7) << 3);
        ah[m] = *(const f16x8*)&As[0][row*64 + ci];
        al[m] = *(const f16x8*)&As[1][row*64 + ci];
      }
      #pragma unroll
      for (int n=0;n<4;n++){
        int row = wc*64 + n*16 + (lane & 15);
        int ci = (kk*32 + ((lane>>4)<<3)) ^ ((row & 7) << 3);
        bh[n] = *(const f16x8*)&Bs[0][row*64 + ci];
        bl[n] = *(const f16x8*)&Bs[1][row*64 + ci];
      }
      #pragma unroll
      for (int m=0;m<4;m++)
        #pragma unroll
        for (int n=0;n<4;n++){
          accA[m][n] = __builtin_amdgcn_mfma_f32_16x16x32_f16(ah[m], bh[n], accA[m][n], 0,0,0);
          accB[m][n] = __builtin_amdgcn_mfma_f32_16x16x32_f16(ah[m], bl[n], accB[m][n], 0,0,0);
          accB[m][n] = __builtin_amdgcn_mfma_f32_16x16x32_f16(al[m], bh[n], accB[m][n], 0,0,0);
        }
    }
    __syncthreads();
  }
  int r0 = (lane >> 4) << 2, c0 = lane & 15;
  #pragma unroll
  for (int m=0;m<4;m++){
    int grow0 = bm*128 + wr*64 + m*16 + r0;
    #pragma unroll
    for (int n=0;n<4;n++){
      int gcol = bn*128 + wc*64 + n*16 + c0;
      #pragma unroll
      for (int j=0;j<4;j++){
        float v = accA[m][n][j] + accB[m][n][j] * (1.f/4096.f);
        int grow = grow0 + j;
        C1[(size_t)grow*N + gcol] += v;
      }
    }
  }
}

// ---------------- MoE down GEMM (1-pass f16, dense A, per-slot store) ----------------
// R18: grid (bn, e, bm) — bm-blocks sharing a B-panel land on one XCD (T1).
__global__ __launch_bounds__(256,2) void k_gemm_down(
    const unsigned short* __restrict__ Aact,
    const float* __restrict__ Bsrc,
    float* __restrict__ yp,
    const int* __restrict__ erow, const int* __restrict__ counts)
{
  const int Kd = FF, N = HDIM;
  int bn = blockIdx.x, e = blockIdx.y, bm = blockIdx.z;
  int cnt = counts[e]; if (bm*128 >= cnt) return;
  const float* Bp = Bsrc + (size_t)e*Kd*N;
  const unsigned short* Abase = Aact + (size_t)e*CCAP*Kd;

  __shared__ unsigned short As[8192];
  __shared__ unsigned short Bs[8192];

  int tid = threadIdx.x, lane = tid & 63, w = tid >> 6;
  int wr = w >> 1, wc = w & 1;

  size_t arow_g[4];
  int lb_[4];
  #pragma unroll
  for (int i=0;i<4;i++){
    int ob = w*4096 + i*1024 + lane*16;
    int row = ob >> 7;
    int colB = ob & 127;
    int scolB = colB ^ ((row & 7) << 4);
    int grow = bm*128 + row;
    arow_g[i] = (size_t)grow * Kd + (scolB >> 1);
    lb_[i] = (w*4096 + i*1024) >> 1;
  }

  f32x4 accA[4][4] = {};

  int nK = Kd >> 6;
  for (int kt = 0; kt < nK; kt++){
    #pragma unroll
    for (int i=0;i<4;i++)
      gl_lds16(Abase + arow_g[i] + kt*64, (void*)&As[lb_[i]]);
    #pragma unroll
    for (int it=0; it<2; it++){
      int b2 = tid + it*256;
      int k0 = (b2 >> 5) << 2;
      int n0 = (b2 & 31) << 2;
      const float* bp = Bp + (size_t)(kt*64 + k0)*N + bn*128 + n0;
      float4 f0 = *(const float4*)bp;
      float4 f1 = *(const float4*)(bp + (size_t)N);
      float4 f2 = *(const float4*)(bp + 2*(size_t)N);
      float4 f3 = *(const float4*)(bp + 3*(size_t)N);
      #define DO_COL(J, CX) { \
        int rown = n0 + J; \
        int idx = rown*64 + (k0 ^ bswz(rown)); \
        u16x4 ph; ph.x=f2h(f0.CX); ph.y=f2h(f1.CX); ph.z=f2h(f2.CX); ph.w=f2h(f3.CX); \
        *(u16x4*)&Bs[idx] = ph; }
      DO_COL(0, x) DO_COL(1, y) DO_COL(2, z) DO_COL(3, w)
      #undef DO_COL
    }
    __syncthreads();
    #pragma unroll
    for (int kk=0; kk<2; kk++){
      f16x8 ah[4], bh[4];
      #pragma unroll
      for (int m=0;m<4;m++){
        int row = wr*64 + m*16 + (lane & 15);
        int ci = (kk*32 + ((lane>>4)<<3)) ^ ((row & 7) << 3);
        ah[m] = *(const f16x8*)&As[row*64 + ci];
      }
      #pragma unroll
      for (int n=0;n<4;n++){
        int row = wc*64 + n*16 + (lane & 15);
        int ci = (kk*32 + ((lane>>4)<<3)) ^ bswz(row);
        bh[n] = *(const f16x8*)&Bs[row*64 + ci];
      }
      #pragma unroll
      for (int m=0;m<4;m++)
        #pragma unroll
        for (int n=0;n<4;n++)
          accA[m][n] = __builtin_amdgcn_mfma_f32_16x16x32_f16(ah[m], bh[n], accA[m][n], 0,0,0);
    }
    __syncthreads();
  }
  int r0 = (lane >> 4) << 2, c0 = lane & 15;
  #pragma unroll
  for (int m=0;m<4;m++){
    int grow0 = bm*128 + wr*64 + m*16 + r0;
    #pragma unroll
    for (int n=0;n<4;n++){
      int gcol = bn*128 + wc*64 + n*16 + c0;
      #pragma unroll
      for (int j=0;j<4;j++){
        int grow = grow0 + j;
        if (grow < cnt){
          int p = erow[e*CCAP + grow];
          yp[(size_t)p*N + gcol] = accA[m][n][j];
        }
      }
    }
  }
}

// ---------------- R16: gu GEMM with fused SiLU ----------------
// R18: grid (bn, e, bm) — bm-blocks sharing a B-panel land on one XCD (T1).
__global__ __launch_bounds__(256,2) void k_gemm_gu(
    const unsigned short* __restrict__ Ahi,
    const float* __restrict__ Bsrc,
    unsigned short* __restrict__ act,
    const int* __restrict__ erow, const int* __restrict__ counts)
{
  const int Kd = HDIM, N = 1536;
  int bn = blockIdx.x, e = blockIdx.y, bm = blockIdx.z;
  int cnt = counts[e]; if (bm*128 >= cnt) return;
  const float* Bp = Bsrc + (size_t)e*Kd*N;

  __shared__ unsigned short As [8192];
  __shared__ unsigned short BsG[8192];
  __shared__ unsigned short BsU[8192];

  int tid = threadIdx.x, lane = tid & 63, w = tid >> 6;
  int wr = w >> 1, wc = w & 1;

  size_t arow_g[4];
  int lb_[4];
  #pragma unroll
  for (int i=0;i<4;i++){
    int ob = w*4096 + i*1024 + lane*16;
    int row = ob >> 7;
    int colB = ob & 127;
    int scolB = colB ^ ((row & 7) << 4);
    int grow = erow[e*CCAP + bm*128 + row] >> 1;
    arow_g[i] = (size_t)grow * Kd + (scolB >> 1);
    lb_[i] = (w*4096 + i*1024) >> 1;
  }

  f32x4 accG[4][4] = {};
  f32x4 accU[4][4] = {};

  for (int kt = 0; kt < Kd/64; kt++){
    #pragma unroll
    for (int i=0;i<4;i++)
      gl_lds16(Ahi + arow_g[i] + kt*64, (void*)&As[lb_[i]]);
    #pragma unroll
    for (int it=0; it<2; it++){
      int b2 = tid + it*256;
      int k0 = (b2 >> 5) << 2;
      int n0 = (b2 & 31) << 2;
      const float* bpg = Bp + (size_t)(kt*64 + k0)*N + bn*128 + n0;
      const float* bpu = bpg + 768;
      float4 g0 = *(const float4*)bpg;
      float4 g1 = *(const float4*)(bpg + (size_t)N);
      float4 g2 = *(const float4*)(bpg + 2*(size_t)N);
      float4 g3 = *(const float4*)(bpg + 3*(size_t)N);
      float4 u0 = *(const float4*)bpu;
      float4 u1 = *(const float4*)(bpu + (size_t)N);
      float4 u2 = *(const float4*)(bpu + 2*(size_t)N);
      float4 u3 = *(const float4*)(bpu + 3*(size_t)N);
      #define DO_COL2(J, CX) { \
        int rown = n0 + J; \
        int idx = rown*64 + (k0 ^ bswz(rown)); \
        u16x4 pg; pg.x=f2h(g0.CX); pg.y=f2h(g1.CX); pg.z=f2h(g2.CX); pg.w=f2h(g3.CX); \
        *(u16x4*)&BsG[idx] = pg; \
        u16x4 pu; pu.x=f2h(u0.CX); pu.y=f2h(u1.CX); pu.z=f2h(u2.CX); pu.w=f2h(u3.CX); \
        *(u16x4*)&BsU[idx] = pu; }
      DO_COL2(0, x) DO_COL2(1, y) DO_COL2(2, z) DO_COL2(3, w)
      #undef DO_COL2
    }
    __syncthreads();
    #pragma unroll
    for (int kk=0; kk<2; kk++){
      f16x8 ah[4], bg[4], bu[4];
      #pragma unroll
      for (int m=0;m<4;m++){
        int row = wr*64 + m*16 + (lane & 15);
        int ci = (kk*32 + ((lane>>4)<<3)) ^ ((row & 7) << 3);
        ah[m] = *(const f16x8*)&As[row*64 + ci];
      }
      #pragma unroll
      for (int n=0;n<4;n++){
        int row = wc*64 + n*16 + (lane & 15);
        int ci = (kk*32 + ((lane>>4)<<3)) ^ bswz(row);
        bg[n] = *(const f16x8*)&BsG[row*64 + ci];
        bu[n] = *(const f16x8*)&BsU[row*64 + ci];
      }
      #pragma unroll
      for (int m=0;m<4;m++)
        #pragma unroll
        for (int n=0;n<4;n++){
          accG[m][n] = __builtin_amdgcn_mfma_f32_16x16x32_f16(ah[m], bg[n], accG[m][n], 0,0,0);
          accU[m][n] = __builtin_amdgcn_mfma_f32_16x16x32_f16(ah[m], bu[n], accU[m][n], 0,0,0);
        }
    }
    __syncthreads();
  }
  int r0 = (lane >> 4) << 2, c0 = lane & 15;
  #pragma unroll
  for (int m=0;m<4;m++){
    int grow0 = bm*128 + wr*64 + m*16 + r0;
    #pragma unroll
    for (int n=0;n<4;n++){
      int gcol = bn*128 + wc*64 + n*16 + c0;
      #pragma unroll
      for (int j=0;j<4;j++){
        int grow = grow0 + j;
        unsigned short g16 = f2h(accG[m][n][j]);
        unsigned short u16_ = f2h(accU[m][n][j]);
        float gf = h2f(g16), uf = h2f(u16_);
        float s = gf / (1.f + __expf(-gf));
        act[((size_t)e*CCAP + grow)*FF + gcol] = f2h(s * uf);
      }
    }
  }
}

// ---------------- flash attention (split-f16 3-pass, causal, GQA) ----------------
// R15 kernel verbatim (247 us best measured). T15 phase pipeline: QK^T of tile
// t+1 computed inside tile t's softmax window (dbuf, stage distance 2);
// setprio around MFMA clusters.
__global__ __launch_bounds__(512,2) void k_attn(
    const unsigned short* __restrict__ qh, const unsigned short* __restrict__ ql,
    const unsigned short* __restrict__ kh, const unsigned short* __restrict__ kl,
    const unsigned short* __restrict__ vh, const unsigned short* __restrict__ vl,
    unsigned short* __restrict__ oh, unsigned short* __restrict__ ol)
{
  int h = blockIdx.y, b = blockIdx.z;
  int qt = b ? (15 - blockIdx.x) : blockIdx.x;    // load-balance pairing
  int hkv = h >> 2;
  int tid = threadIdx.x, lane = tid & 63, w = tid >> 6;   // 8 waves

  __shared__ unsigned short Ks[2][2][8192];  // [buf][plane][kv64 x d128], XOR-16B swizzled
  __shared__ unsigned short Vs[2][2][8192];  // [buf][plane][d128 x kv64] transposed, XOR-8 swizzled
  __shared__ unsigned short Ps[8][2][1024];  // per-wave [r16 x kv64]

  int qrow = qt*128 + w*16 + (lane & 15);
  size_t qoff = ((size_t)(b*SEQ + qrow)*NHQ + h)*DH + ((lane>>4)<<3);
  f16x8 qfh[4], qfl[4];
  #pragma unroll
  for (int kk=0; kk<4; kk++){
    qfh[kk] = *(const f16x8*)(qh + qoff + kk*32);
    qfl[kk] = *(const f16x8*)(ql + qoff + kk*32);
  }

  const size_t SROW = (size_t)NKVH*DH;
  size_t kvbase = (size_t)b*SEQ*SROW + (size_t)hkv*DH;
  int kob[2]; size_t koff[2];
  #pragma unroll
  for (int i=0;i<2;i++){
    int ob = i*8192 + tid*16;
    int row = ob >> 8;
    int scol = (ob & 255) ^ ((row & 7) << 4);
    kob[i] = ob;
    koff[i] = (size_t)row*SROW + (scol >> 1);
  }
  int vkvp = (tid & 31) * 2;
  int vd0  = ((tid >> 5) & 15) * 8;
  size_t voff0 = (size_t)vkvp*SROW + vd0;
  size_t voff1 = voff0 + SROW;

  u16x8 pkh[2], pkl[2];
  u16x8 pvh[2], pvl[2];

  #define STAGE_LOAD(KVT) { \
    size_t tb = kvbase + (size_t)(KVT)*64*SROW; \
    _Pragma("unroll") \
    for (int i=0;i<2;i++){ pkh[i] = *(const u16x8*)(kh + tb + koff[i]); \
                           pkl[i] = *(const u16x8*)(kl + tb + koff[i]); } \
    pvh[0] = *(const u16x8*)(vh + tb + voff0); \
    pvh[1] = *(const u16x8*)(vh + tb + voff1); \
    pvl[0] = *(const u16x8*)(vl + tb + voff0); \
    pvl[1] = *(const u16x8*)(vl + tb + voff1); }

  #define STAGE_WRITE(BUF) { \
    _Pragma("unroll") \
    for (int i=0;i<2;i++){ \
      *(u16x8*)((char*)&Ks[BUF][0][0] + kob[i]) = pkh[i]; \
      *(u16x8*)((char*)&Ks[BUF][1][0] + kob[i]) = pkl[i]; } \
    _Pragma("unroll") \
    for (int jj=0;jj<8;jj++){ \
      int row = vd0 + jj; \
      int idx = row*64 + (vkvp ^ ((jj & 7) << 3)); \
      *(unsigned int*)&Vs[BUF][0][idx] = (unsigned int)pvh[0][jj] | ((unsigned int)pvh[1][jj] << 16); \
      *(unsigned int*)&Vs[BUF][1][idx] = (unsigned int)pvl[0][jj] | ((unsigned int)pvl[1][jj] << 16); } }

  // scores for tile KVT from buffer BUF -> p[4][4], mx[4] (combine+mask+lane max)
  #define QKT(KVT, BUF) { \
    f32x4 saA[4] = {}; \
    f32x4 saB[4] = {}; \
    __builtin_amdgcn_s_setprio(1); \
    _Pragma("unroll") \
    for (int kk=0; kk<4; kk++){ \
      _Pragma("unroll") \
      for (int n=0;n<4;n++){ \
        int row = n*16 + (lane & 15); \
        int ci = (kk*32 + ((lane>>4)<<3)) ^ ((row & 7) << 3); \
        f16x8 kfh = *(const f16x8*)&Ks[BUF][0][row*128 + ci]; \
        f16x8 kfl = *(const f16x8*)&Ks[BUF][1][row*128 + ci]; \
        saA[n] = __builtin_amdgcn_mfma_f32_16x16x32_f16(qfh[kk], kfh, saA[n], 0,0,0); \
        saB[n] = __builtin_amdgcn_mfma_f32_16x16x32_f16(qfh[kk], kfl, saB[n], 0,0,0); \
        saB[n] = __builtin_amdgcn_mfma_f32_16x16x32_f16(qfl[kk], kfh, saB[n], 0,0,0); } } \
    __builtin_amdgcn_s_setprio(0); \
    _Pragma("unroll") \
    for (int j=0;j<4;j++) mx[j] = -1e30f; \
    int qg = qt*128 + w*16 + ((lane>>4)<<2); \
    _Pragma("unroll") \
    for (int n=0;n<4;n++){ \
      int kvcol = (KVT)*64 + n*16 + (lane & 15); \
      _Pragma("unroll") \
      for (int j=0;j<4;j++){ \
        float sv = saA[n][j] + saB[n][j]*(1.f/4096.f); \
        if (kvcol > qg + j) sv = -1e30f; \
        p[n][j] = sv; \
        mx[j] = fmaxf(mx[j], sv); } } }

  // online-softmax update; consumes p/mx into Ps[w] + rescales oacc
  #define SOFTMAX() { \
    _Pragma("unroll") \
    for (int sh=1; sh<16; sh<<=1) \
      _Pragma("unroll") \
      for (int j=0;j<4;j++) mx[j] = fmaxf(mx[j], __shfl_xor(mx[j], sh)); \
    float rs[4], sum[4]; \
    _Pragma("unroll") \
    for (int j=0;j<4;j++){ \
      float mn = fmaxf(m_[j], mx[j]); \
      rs[j] = __expf(m_[j] - mn); \
      float sm = 0.f; \
      _Pragma("unroll") \
      for (int n=0;n<4;n++){ float pe = __expf(p[n][j] - mn); p[n][j] = pe; sm += pe; } \
      sum[j] = sm; \
      m_[j] = mn; } \
    _Pragma("unroll") \
    for (int sh=1; sh<16; sh<<=1) \
      _Pragma("unroll") \
      for (int j=0;j<4;j++) sum[j] += __shfl_xor(sum[j], sh); \
    _Pragma("unroll") \
    for (int j=0;j<4;j++) l_[j] = l_[j]*rs[j] + sum[j]; \
    _Pragma("unroll") \
    for (int d=0;d<8;d++) \
      _Pragma("unroll") \
      for (int j=0;j<4;j++){ oaccA[d][j] *= rs[j]; oaccB[d][j] *= rs[j]; } \
    _Pragma("unroll") \
    for (int n=0;n<4;n++) \
      _Pragma("unroll") \
      for (int j=0;j<4;j++){ \
        int r = ((lane>>4)<<2) + j; \
        int c = n*16 + (lane & 15); \
        int idx = r*64 + (c ^ ((r & 7) << 3)); \
        unsigned short ph, pl2; split2(p[n][j], ph, pl2); \
        Ps[w][0][idx] = ph; \
        Ps[w][1][idx] = pl2; } }

  #define PVOP(BUF) { \
    __builtin_amdgcn_s_setprio(1); \
    _Pragma("unroll") \
    for (int kk=0; kk<2; kk++){ \
      int prow = lane & 15; \
      int pidx = prow*64 + ((kk*32 + ((lane>>4)<<3)) ^ ((prow & 7) << 3)); \
      f16x8 pah = *(const f16x8*)&Ps[w][0][pidx]; \
      f16x8 pal = *(const f16x8*)&Ps[w][1][pidx]; \
      _Pragma("unroll") \
      for (int d=0;d<8;d++){ \
        int row = d*16 + (lane & 15); \
        int ci = (kk*32 + ((lane>>4)<<3)) ^ ((row & 7) << 3); \
        f16x8 vfh = *(const f16x8*)&Vs[BUF][0][row*64 + ci]; \
        f16x8 vfl = *(const f16x8*)&Vs[BUF][1][row*64 + ci]; \
        oaccA[d] = __builtin_amdgcn_mfma_f32_16x16x32_f16(pah, vfh, oaccA[d], 0,0,0); \
        oaccB[d] = __builtin_amdgcn_mfma_f32_16x16x32_f16(pah, vfl, oaccB[d], 0,0,0); \
        oaccB[d] = __builtin_amdgcn_mfma_f32_16x16x32_f16(pal, vfh, oaccB[d], 0,0,0); } } \
    __builtin_amdgcn_s_setprio(0); }

  float m_[4], l_[4];
  f32x4 oaccA[8] = {};
  f32x4 oaccB[8] = {};
  #pragma unroll
  for (int j=0;j<4;j++){ m_[j] = -1e30f; l_[j] = 0.f; }

  int nkt = 2*qt + 2;                 // >= 2 always
  STAGE_LOAD(0); STAGE_WRITE(0);
  STAGE_LOAD(1); STAGE_WRITE(1);
  __syncthreads();

  float p[4][4], mx[4];
  QKT(0, 0);                          // tile 0 is active for every wave

  for (int kvt = 0; kvt < nkt; kvt++){
    int cur = kvt & 1, nxt = cur ^ 1;
    if (kvt+2 < nkt) STAGE_LOAD(kvt+2);

    bool active = (kvt*64 <= qt*128 + w*16 + 15);
    bool actn   = (kvt+1 < nkt) && ((kvt+1)*64 <= qt*128 + w*16 + 15);
    if (actn){
      // one straight-line region: softmax(t) VALU overlaps QKT(t+1) MFMA
      SOFTMAX();
      QKT(kvt+1, nxt);
      PVOP(cur);
    } else if (active){
      SOFTMAX();
      PVOP(cur);
    }
    __syncthreads();                  // all reads of buf[cur] (V of tile t) done
    if (kvt+2 < nkt) STAGE_WRITE(cur);
    __syncthreads();                  // publish tile t+2 for iter t+1's QKT
  }
  #undef STAGE_LOAD
  #undef STAGE_WRITE
  #undef QKT
  #undef SOFTMAX
  #undef PVOP

  #pragma unroll
  for (int j=0;j<4;j++) l_[j] = 1.f / l_[j];
  #pragma unroll
  for (int d=0;d<8;d++)
    #pragma unroll
    for (int j=0;j<4;j++){
      int qr = qt*128 + w*16 + ((lane>>4)<<2) + j;
      size_t off = ((size_t)(b*SEQ + qr)*NHQ + h)*DH + d*16 + (lane & 15);
      float v = (oaccA[d][j] + oaccB[d][j]*(1.f/4096.f)) * l_[j];
      unsigned short hi, lo; split2(v, hi, lo);
      oh[off] = hi; ol[off] = lo;
    }
}

// ---------------- fused post-attn RMSNorm -> x2  +  gate top-2 ----------------
// R19: gate-logit reduction via wave shuffle butterfly (6 steps) + one LDS
// cross-wave step — replaces the 8-barrier [256][16]-double tree. Reduction
// order changes logits at ~1e-13 (far below tolerance).
__global__ __launch_bounds__(256) void k_ln2gate(
    const float* __restrict__ resid, const float* __restrict__ wln,
    const float* __restrict__ gw,
    unsigned short* __restrict__ x2, float* __restrict__ topw, int* __restrict__ topid)
{
  int t = blockIdx.x, tid = threadIdx.x;
  size_t off = (size_t)t * HDIM;
  float4 s0 = ((const float4*)(resid+off))[tid];
  float4 s1 = ((const float4*)(resid+off))[tid+256];
  float ssq = s0.x*s0.x+s0.y*s0.y+s0.z*s0.z+s0.w*s0.w
            + s1.x*s1.x+s1.y*s1.y+s1.z*s1.z+s1.w*s1.w;
  #pragma unroll
  for (int sh=1; sh<64; sh<<=1) ssq += __shfl_xor(ssq, sh);
  __shared__ float red[4];
  if ((tid & 63) == 0) red[tid>>6] = ssq;
  __syncthreads();
  float tot = red[0]+red[1]+red[2]+red[3];
  float r = 1.f / sqrtf(tot * (1.f/HDIM) + EPSF);
  float4 w0 = ((const float4*)wln)[tid];
  float4 w1 = ((const float4*)wln)[tid+256];
  float xs[8] = { s0.x*r*w0.x, s0.y*r*w0.y, s0.z*r*w0.z, s0.w*r*w0.w,
                  s1.x*r*w1.x, s1.y*r*w1.y, s1.z*r*w1.z, s1.w*r*w1.w };
  u16x4 hv;
  hv.x = f2h(xs[0]); hv.y = f2h(xs[1]); hv.z = f2h(xs[2]); hv.w = f2h(xs[3]);
  ((u16x4*)(x2+off))[tid] = hv;
  hv.x = f2h(xs[4]); hv.y = f2h(xs[5]); hv.z = f2h(xs[6]); hv.w = f2h(xs[7]);
  ((u16x4*)(x2+off))[tid+256] = hv;

  double acc[16];
  #pragma unroll
  for (int e2=0;e2<16;e2++) acc[e2] = 0.0;
  #pragma unroll
  for (int i=0;i<8;i++){
    int hidx = (i<4) ? (tid*4 + i) : (1024 + tid*4 + (i-4));
    const float4* g4 = (const float4*)(gw + (size_t)hidx*NE);
    float4 ga=g4[0], gb=g4[1], gc=g4[2], gd=g4[3];
    double xx = (double)xs[i];
    acc[0]+=xx*ga.x;  acc[1]+=xx*ga.y;  acc[2]+=xx*ga.z;  acc[3]+=xx*ga.w;
    acc[4]+=xx*gb.x;  acc[5]+=xx*gb.y;  acc[6]+=xx*gb.z;  acc[7]+=xx*gb.w;
    acc[8]+=xx*gc.x;  acc[9]+=xx*gc.y;  acc[10]+=xx*gc.z; acc[11]+=xx*gc.w;
    acc[12]+=xx*gd.x; acc[13]+=xx*gd.y; acc[14]+=xx*gd.z; acc[15]+=xx*gd.w;
  }
  // wave-level butterfly reduce (doubles), then one cross-wave LDS step
  #pragma unroll
  for (int sh=1; sh<64; sh<<=1)
    #pragma unroll
    for (int e2=0;e2<16;e2++) acc[e2] += __shfl_xor(acc[e2], sh);
  __shared__ double red2[4][16];
  if ((tid & 63) == 0){
    #pragma unroll
    for (int e2=0;e2<16;e2++) red2[tid>>6][e2] = acc[e2];
  }
  __syncthreads();
  if (tid == 0){
    float l[16];
    #pragma unroll
    for (int e2=0;e2<16;e2++)
      l[e2] = (float)(red2[0][e2] + red2[1][e2] + red2[2][e2] + red2[3][e2]);
    int i0 = 0;
    #pragma unroll
    for (int e2=1;e2<16;e2++) if (l[e2] > l[i0]) i0 = e2;
    int i1 = (i0 == 0) ? 1 : 0;
    #pragma unroll
    for (int e2=0;e2<16;e2++) if (e2 != i0 && l[e2] > l[i1]) i1 = e2;
    float w0t = 1.f / (1.f + expf(l[i1] - l[i0]));
    topw[t*2+0] = w0t; topw[t*2+1] = 1.f - w0t;
    topid[t*2+0] = i0; topid[t*2+1] = i1;
  }
}

// ---------------- routing: exact stable counting sort ----------------
__global__ __launch_bounds__(256) void k_route(
    int* __restrict__ topid, int* __restrict__ erow, int* __restrict__ counts)
{
  int tid = threadIdx.x;
  __shared__ unsigned short cnt[256][16];
  for (int i = tid; i < NE*CCAP; i += 256) erow[i] = 0;
  int loc[16];
  #pragma unroll
  for (int e2=0;e2<16;e2++) loc[e2] = 0;
  int myid[32];
  for (int i=0;i<32;i++){
    int e2 = topid[tid*32 + i];
    myid[i] = e2;
    loc[e2]++;
  }
  #pragma unroll
  for (int e2=0;e2<16;e2++) cnt[tid][e2] = (unsigned short)loc[e2];
  __syncthreads();
  if (tid < 16){
    int run = 0;
    for (int i=0;i<256;i++){ int c = cnt[i][tid]; cnt[i][tid] = (unsigned short)run; run += c; }
    counts[tid] = run > CCAP ? CCAP : run;
  }
  __syncthreads();
  #pragma unroll
  for (int e2=0;e2<16;e2++) loc[e2] = cnt[tid][e2];
  for (int i=0;i<32;i++){
    int e2 = myid[i];
    int pos = loc[e2]++;
    int p = tid*32 + i;
    int ok = (pos < CCAP);
    if (ok) erow[e2*CCAP + pos] = p;
    topid[p] = ok;                      // recycle topid as slot-valid flag
  }
}

// ---------------- R6: gather per-slot down rows -> weighted token sum ----------------
__global__ __launch_bounds__(256) void k_gather(
    const float* __restrict__ yp, const int* __restrict__ valid,
    const float* __restrict__ topw, float* __restrict__ y)
{
  int t = blockIdx.x, tid = threadIdx.x;
  int v0 = valid[t*2+0], v1 = valid[t*2+1];
  float w0 = topw[t*2+0], w1 = topw[t*2+1];
  size_t o = (size_t)t*2*HDIM;
  const float4* r0 = (const float4*)(yp + o);
  const float4* r1 = (const float4*)(yp + o + HDIM);
  float4* yo = (float4*)(y + (size_t)t*HDIM);
  #pragma unroll
  for (int i=0;i<2;i++){
    int ix = tid + i*256;
    float4 a = r0[ix];
    float4 b = r1[ix];
    float4 out;
    float a0 = v0 ? w0 : 0.f;
    float b0 = v1 ? w1 : 0.f;
    out.x = (v0 ? a.x*a0 : 0.f) + (v1 ? b.x*b0 : 0.f);
    out.y = (v0 ? a.y*a0 : 0.f) + (v1 ? b.y*b0 : 0.f);
    out.z = (v0 ? a.z*a0 : 0.f) + (v1 ? b.z*b0 : 0.f);
    out.w = (v0 ? a.w*a0 : 0.f) + (v1 ? b.w*b0 : 0.f);
    yo[ix] = out;
  }
}

extern "C" void kernel_launch(void* const* d_in, const int* in_sizes, int n_in,
                              void* d_out, int out_size, void* d_ws, size_t ws_size,
                              hipStream_t stream)
{
  (void)in_sizes; (void)n_in; (void)out_size; (void)ws_size;
  const int*   positions = (const int*)  d_in[0];
  const float* hs        = (const float*)d_in[1];
  const float* res       = (const float*)d_in[2];
  const float* w_in_ln   = (const float*)d_in[3];
  const float* wq        = (const float*)d_in[4];
  const float* wk        = (const float*)d_in[5];
  const float* wv        = (const float*)d_in[6];
  const float* wo        = (const float*)d_in[7];
  const float* q_norm_w  = (const float*)d_in[8];
  const float* k_norm_w  = (const float*)d_in[9];
  const float* w_post_ln = (const float*)d_in[10];
  const float* gate_w    = (const float*)d_in[11];
  const float* w_gate_up = (const float*)d_in[12];
  const float* w_down    = (const float*)d_in[13];

  float* y      = (float*)d_out;
  float* resid2 = y + (size_t)T_TOK*HDIM;

  char* ws = (char*)d_ws;
  unsigned short* hhi = (unsigned short*)(ws + 0);
  unsigned short* hlo = (unsigned short*)(ws + 16777216);
  unsigned short* qh  = (unsigned short*)(ws + 33554432);
  unsigned short* ql  = (unsigned short*)(ws + 50331648);
  unsigned short* kh  = (unsigned short*)(ws + 67108864);
  unsigned short* kl  = (unsigned short*)(ws + 71303168);
  unsigned short* vh  = (unsigned short*)(ws + 75497472);
  unsigned short* vl  = (unsigned short*)(ws + 79691776);
  unsigned short* oh  = (unsigned short*)(ws + 83886080);
  unsigned short* ol  = (unsigned short*)(ws + 100663296);
  unsigned short* x2  = (unsigned short*)(ws + 117440512);
  // R13 weight-plane overlays (time-disjoint with oh/ol and x2):
  unsigned short* qkvwh = (unsigned short*)(ws + 83886080);  // 12.58 MB
  unsigned short* qkvwl = (unsigned short*)(ws + 96468992);  // 12.58 MB
  unsigned short* wowh  = (unsigned short*)(ws + 117440512); // 8.39 MB
  unsigned short* wowl  = (unsigned short*)(ws + 125829120); // 8.39 MB
  // MoE-phase overlays (attention-phase buffers are dead by then):
  unsigned short* act = (unsigned short*)(ws + 67108864);    // [gemm_gu, gemm_down]
  float*          yp  = (float*)         (ws + 0);           // [gemm_down, gather]
  float* cstab        = (float*)(ws + 134217728);
  float* topw         = (float*)(ws + 135266304);
  int*   topid        = (int*)  (ws + 135299072);
  int*   counts       = (int*)  (ws + 135331840);
  int*   erow         = (int*)  (ws + 135332096);

  k_addnorm<<<T_TOK, 256, 0, stream>>>(hs, res, w_in_ln, resid2, hhi, hlo);
  k_cstab<<<(SEQ*64 + 255)/256, 256, 0, stream>>>(positions, cstab);
  // one-time weight split+transpose (R13; R19 merged QKV into one launch)
  k_wsplit3<<<dim3(32, 48), 256, 0, stream>>>(wq, wk, wv, qkvwh, qkvwl);
  k_wsplit<<<dim3(32, 32), 256, 0, stream>>>(wo, HDIM, 2048, wowh, wowl);
  k_gemm_qkv<<<dim3(32,24,1), 256, 0, stream>>>(hhi, hlo, qkvwh, qkvwl, qh, ql, kh, kl, vh, vl);
  k_normrope<<<dim3(T_TOK, 5), 256, 0, stream>>>(qh, ql, kh, kl, q_norm_w, k_norm_w, cstab);
  k_attn<<<dim3(16, 16, 2), 512, 0, stream>>>(qh, ql, kh, kl, vh, vl, oh, ol);
  k_gemm_o<<<dim3(32,16,1), 256, 0, stream>>>(oh, ol, wowh, wowl, resid2);
  k_ln2gate<<<T_TOK, 256, 0, stream>>>(resid2, w_post_ln, gate_w, x2, topw, topid);
  k_route<<<1, 256, 0, stream>>>(topid, erow, counts);
  k_gemm_gu<<<dim3(6,16,8), 256, 0, stream>>>(x2, w_gate_up, act, erow, counts);
  k_gemm_down<<<dim3(16,16,8), 256, 0, stream>>>(act, w_down, yp, erow, counts);
  k_gather<<<T_TOK, 256, 0, stream>>>(yp, topid, topw, y);
}

// Round 15
// 841.324 us; speedup vs baseline: 1.0320x; 1.0320x over previous
//
#include <hip/hip_runtime.h>
#include <stdint.h>

#define T_TOK 4096
#define HDIM  2048
#define SEQ   2048
#define NHQ   16
#define NKVH  4
#define DH    128
#define NE    16
#define CCAP  1024
#define FF    768
#define EPSF  1e-6f

typedef __attribute__((ext_vector_type(4))) float          f32x4;
typedef __attribute__((ext_vector_type(8))) _Float16       f16x8;
typedef __attribute__((ext_vector_type(4))) unsigned short u16x4;
typedef __attribute__((ext_vector_type(8))) unsigned short u16x8;

__device__ __forceinline__ unsigned short f2h(float f){ return __builtin_bit_cast(unsigned short, (_Float16)f); }
__device__ __forceinline__ float h2f(unsigned short u){ return (float)__builtin_bit_cast(_Float16, u); }
__device__ __forceinline__ void split2(float x, unsigned short& hi, unsigned short& lo){
  unsigned short h = f2h(x);
  hi = h; lo = f2h((x - h2f(h)) * 4096.f);
}
__device__ __forceinline__ void gl_lds16(const void* g, void* l){
  __builtin_amdgcn_global_load_lds((const __attribute__((address_space(1))) unsigned int*)g,
                                   (__attribute__((address_space(3))) unsigned int*)l, 16, 0, 0);
}
// R7: B-side LDS swizzle for the on-the-fly f32 path (MoE GEMMs only now).
__device__ __forceinline__ int bswz(int row){ return ((row & 7) ^ ((row >> 3) & 7)) << 3; }

// ---------------- residual add + RMSNorm -> split f16 h ----------------
__global__ __launch_bounds__(256) void k_addnorm(
    const float* __restrict__ hs, const float* __restrict__ rs, const float* __restrict__ w,
    float* __restrict__ resid, unsigned short* __restrict__ hhi, unsigned short* __restrict__ hlo)
{
  int t = blockIdx.x, tid = threadIdx.x;
  size_t off = (size_t)t * HDIM;
  float4 a0 = ((const float4*)(hs+off))[tid];
  float4 b0 = ((const float4*)(rs+off))[tid];
  float4 a1 = ((const float4*)(hs+off))[tid+256];
  float4 b1 = ((const float4*)(rs+off))[tid+256];
  float4 s0 = make_float4(a0.x+b0.x, a0.y+b0.y, a0.z+b0.z, a0.w+b0.w);
  float4 s1 = make_float4(a1.x+b1.x, a1.y+b1.y, a1.z+b1.z, a1.w+b1.w);
  float ssq = s0.x*s0.x+s0.y*s0.y+s0.z*s0.z+s0.w*s0.w
            + s1.x*s1.x+s1.y*s1.y+s1.z*s1.z+s1.w*s1.w;
  #pragma unroll
  for (int sh=1; sh<64; sh<<=1) ssq += __shfl_xor(ssq, sh);
  __shared__ float red[4];
  if ((tid & 63) == 0) red[tid>>6] = ssq;
  __syncthreads();
  float tot = red[0]+red[1]+red[2]+red[3];
  float r = 1.f / sqrtf(tot * (1.f/HDIM) + EPSF);
  ((float4*)(resid+off))[tid]     = s0;
  ((float4*)(resid+off))[tid+256] = s1;
  float4 w0 = ((const float4*)w)[tid];
  float4 w1 = ((const float4*)w)[tid+256];
  u16x4 hv, lv; unsigned short ta, tb;
  split2(s0.x*r*w0.x, ta, tb); hv.x=ta; lv.x=tb;
  split2(s0.y*r*w0.y, ta, tb); hv.y=ta; lv.y=tb;
  split2(s0.z*r*w0.z, ta, tb); hv.z=ta; lv.z=tb;
  split2(s0.w*r*w0.w, ta, tb); hv.w=ta; lv.w=tb;
  ((u16x4*)(hhi+off))[tid] = hv; ((u16x4*)(hlo+off))[tid] = lv;
  split2(s1.x*r*w1.x, ta, tb); hv.x=ta; lv.x=tb;
  split2(s1.y*r*w1.y, ta, tb); hv.y=ta; lv.y=tb;
  split2(s1.z*r*w1.z, ta, tb); hv.z=ta; lv.z=tb;
  split2(s1.w*r*w1.w, ta, tb); hv.w=ta; lv.w=tb;
  ((u16x4*)(hhi+off))[tid+256] = hv; ((u16x4*)(hlo+off))[tid+256] = lv;
}

// ---------------- RoPE cos/sin table (match np f32 powf via f64) ----------------
__global__ void k_cstab(const int* __restrict__ pos, float* __restrict__ cs)
{
  int i = blockIdx.x*256 + threadIdx.x;
  if (i >= SEQ*64) return;
  int s = i >> 6, f = i & 63;
  float pw  = (float)exp((double)f * 13.815510557964274 / 64.0); // 1e6^(f/64), CR to f32
  float inv = 1.0f / pw;                                          // two roundings, like reference
  float ang = (float)pos[s] * inv;
  float sv, cv;
  sincosf(ang, &sv, &cv);
  ((float2*)cs)[i] = make_float2(cv, sv);
}

// ---------------- per-head RMSNorm + RoPE (4 heads/block) ----------------
__global__ __launch_bounds__(256) void k_normrope(
    unsigned short* __restrict__ qh, unsigned short* __restrict__ ql,
    unsigned short* __restrict__ kh, unsigned short* __restrict__ kl,
    const float* __restrict__ qnw, const float* __restrict__ knw,
    const float* __restrict__ cs)
{
  int t = blockIdx.x, head = blockIdx.y*4 + (threadIdx.x>>6), lane = threadIdx.x & 63;
  int s = t & (SEQ-1);
  unsigned short *dh, *dl; const float* wn; float scale; size_t off;
  if (head < NHQ){ off = ((size_t)t*NHQ + head)*DH; dh = qh+off; dl = ql+off; wn = qnw; scale = 0.08838834764831845f; }
  else           { off = ((size_t)t*NKVH + (head-NHQ))*DH; dh = kh+off; dl = kl+off; wn = knw; scale = 1.f; }
  float x1 = h2f(dh[lane])    + h2f(dl[lane])   *(1.f/4096.f);
  float x2 = h2f(dh[lane+64]) + h2f(dl[lane+64])*(1.f/4096.f);
  float ssq = x1*x1 + x2*x2;
  #pragma unroll
  for (int sh=1; sh<64; sh<<=1) ssq += __shfl_xor(ssq, sh);
  float r = 1.f / sqrtf(ssq * (1.f/DH) + EPSF);
  float y1 = x1*r*wn[lane], y2 = x2*r*wn[lane+64];
  float2 csp = ((const float2*)cs)[s*64 + lane];
  float o1 = (y1*csp.x - y2*csp.y) * scale;
  float o2 = (y2*csp.x + y1*csp.y) * scale;
  unsigned short a, b;
  split2(o1, a, b); dh[lane]    = a; dl[lane]    = b;
  split2(o2, a, b); dh[lane+64] = a; dl[lane+64] = b;
}

// ---------------- R13: one-time weight split+transpose ----------------
// W [Kd][Ncols] f32  ->  Whi/Wlo [Ncols][Kd] u16 (transposed, split2 planes).
__global__ __launch_bounds__(256) void k_wsplit(
    const float* __restrict__ W, int Kd, int Ncols,
    unsigned short* __restrict__ Whi, unsigned short* __restrict__ Wlo)
{
  int k0 = blockIdx.x*64, n0 = blockIdx.y*64;
  __shared__ float T[64][65];
  int tid = threadIdx.x;
  int tr = tid >> 4;
  int tc = (tid & 15) * 4;
  #pragma unroll
  for (int i=0;i<4;i++){
    int k = tr + i*16;
    float4 v = *(const float4*)(W + (size_t)(k0 + k)*Ncols + n0 + tc);
    T[k][tc+0]=v.x; T[k][tc+1]=v.y; T[k][tc+2]=v.z; T[k][tc+3]=v.w;
  }
  __syncthreads();
  int n  = tid >> 2;
  int kc = (tid & 3) * 16;
  u16x8 hv0, lv0, hv1, lv1;
  #pragma unroll
  for (int j=0;j<8;j++){
    unsigned short hi, lo; split2(T[kc+j][n], hi, lo);
    hv0[j]=hi; lv0[j]=lo;
  }
  #pragma unroll
  for (int j=0;j<8;j++){
    unsigned short hi, lo; split2(T[kc+8+j][n], hi, lo);
    hv1[j]=hi; lv1[j]=lo;
  }
  size_t ob = (size_t)(n0 + n)*Kd + k0 + kc;
  *(u16x8*)(Whi + ob)     = hv0;
  *(u16x8*)(Whi + ob + 8) = hv1;
  *(u16x8*)(Wlo + ob)     = lv0;
  *(u16x8*)(Wlo + ob + 8) = lv1;
}

// ---------------- R19: merged QKV weight split (one launch; kept from R19) ----------------
// grid (32, 48): y<32 -> wq (2048 cols), 32..39 -> wk (512), 40..47 -> wv (512).
__global__ __launch_bounds__(256) void k_wsplit3(
    const float* __restrict__ wq, const float* __restrict__ wk, const float* __restrict__ wv,
    unsigned short* __restrict__ Whi, unsigned short* __restrict__ Wlo)
{
  const int Kd = HDIM;
  int k0 = blockIdx.x*64, ny = blockIdx.y;
  const float* W; int Ncols, n0, noff;
  if (ny < 32){ W = wq; Ncols = 2048; n0 = ny*64;      noff = 0;    }
  else if (ny < 40){ W = wk; Ncols = 512; n0 = (ny-32)*64; noff = 2048; }
  else { W = wv; Ncols = 512; n0 = (ny-40)*64; noff = 2560; }
  __shared__ float T[64][65];
  int tid = threadIdx.x;
  int tr = tid >> 4;
  int tc = (tid & 15) * 4;
  #pragma unroll
  for (int i=0;i<4;i++){
    int k = tr + i*16;
    float4 v = *(const float4*)(W + (size_t)(k0 + k)*Ncols + n0 + tc);
    T[k][tc+0]=v.x; T[k][tc+1]=v.y; T[k][tc+2]=v.z; T[k][tc+3]=v.w;
  }
  __syncthreads();
  int n  = tid >> 2;
  int kc = (tid & 3) * 16;
  u16x8 hv0, lv0, hv1, lv1;
  #pragma unroll
  for (int j=0;j<8;j++){
    unsigned short hi, lo; split2(T[kc+j][n], hi, lo);
    hv0[j]=hi; lv0[j]=lo;
  }
  #pragma unroll
  for (int j=0;j<8;j++){
    unsigned short hi, lo; split2(T[kc+8+j][n], hi, lo);
    hv1[j]=hi; lv1[j]=lo;
  }
  size_t ob = (size_t)(noff + n0 + n)*Kd + k0 + kc;
  *(u16x8*)(Whi + ob)     = hv0;
  *(u16x8*)(Whi + ob + 8) = hv1;
  *(u16x8*)(Wlo + ob)     = lv0;
  *(u16x8*)(Wlo + ob + 8) = lv1;
}

// ---------------- fused QKV GEMM (split-f16 3-pass, pre-split B) ----------------
// grid (32, 24): bn2<16 -> Q, 16..19 -> K, 20..23 -> V
__global__ __launch_bounds__(256,2) void k_gemm_qkv(
    const unsigned short* __restrict__ Ahi, const unsigned short* __restrict__ Alo,
    const unsigned short* __restrict__ Whi, const unsigned short* __restrict__ Wlo,
    unsigned short* __restrict__ qh, unsigned short* __restrict__ ql,
    unsigned short* __restrict__ kh, unsigned short* __restrict__ kl,
    unsigned short* __restrict__ vh, unsigned short* __restrict__ vl)
{
  const int Kd = HDIM;
  int bm = blockIdx.x, bn2 = blockIdx.y;
  int bn, N, noff; unsigned short *Ch, *Cl;
  if (bn2 < 16){ bn = bn2;      N = 2048; noff = 0;    Ch = qh; Cl = ql; }
  else if (bn2 < 20){ bn = bn2-16; N = 512; noff = 2048; Ch = kh; Cl = kl; }
  else { bn = bn2-20; N = 512; noff = 2560; Ch = vh; Cl = vl; }

  __shared__ unsigned short As[2][8192];
  __shared__ unsigned short Bs[2][8192];

  int tid = threadIdx.x, lane = tid & 63, w = tid >> 6;
  int wr = w >> 1, wc = w & 1;

  size_t arow_g[4], brow_g[4];
  int lb_[4];
  #pragma unroll
  for (int i=0;i<4;i++){
    int ob = w*4096 + i*1024 + lane*16;
    int row = ob >> 7;
    int colB = ob & 127;
    int scolB = colB ^ ((row & 7) << 4);
    arow_g[i] = (size_t)(bm*128 + row) * Kd + (scolB >> 1);
    brow_g[i] = (size_t)(noff + bn*128 + row) * Kd + (scolB >> 1);
    lb_[i] = (w*4096 + i*1024) >> 1;
  }

  f32x4 accA[4][4] = {};
  f32x4 accB[4][4] = {};

  for (int kt = 0; kt < Kd/64; kt++){
    #pragma unroll
    for (int i=0;i<4;i++){
      gl_lds16(Ahi + arow_g[i] + kt*64, (void*)&As[0][lb_[i]]);
      gl_lds16(Alo + arow_g[i] + kt*64, (void*)&As[1][lb_[i]]);
      gl_lds16(Whi + brow_g[i] + kt*64, (void*)&Bs[0][lb_[i]]);
      gl_lds16(Wlo + brow_g[i] + kt*64, (void*)&Bs[1][lb_[i]]);
    }
    __syncthreads();
    #pragma unroll
    for (int kk=0; kk<2; kk++){
      f16x8 ah[4], al[4], bh[4], bl[4];
      #pragma unroll
      for (int m=0;m<4;m++){
        int row = wr*64 + m*16 + (lane & 15);
        int ci = (kk*32 + ((lane>>4)<<3)) ^ ((row & 7) << 3);
        ah[m] = *(const f16x8*)&As[0][row*64 + ci];
        al[m] = *(const f16x8*)&As[1][row*64 + ci];
      }
      #pragma unroll
      for (int n=0;n<4;n++){
        int row = wc*64 + n*16 + (lane & 15);
        int ci = (kk*32 + ((lane>>4)<<3)) ^ ((row & 7) << 3);
        bh[n] = *(const f16x8*)&Bs[0][row*64 + ci];
        bl[n] = *(const f16x8*)&Bs[1][row*64 + ci];
      }
      #pragma unroll
      for (int m=0;m<4;m++)
        #pragma unroll
        for (int n=0;n<4;n++){
          accA[m][n] = __builtin_amdgcn_mfma_f32_16x16x32_f16(ah[m], bh[n], accA[m][n], 0,0,0);
          accB[m][n] = __builtin_amdgcn_mfma_f32_16x16x32_f16(ah[m], bl[n], accB[m][n], 0,0,0);
          accB[m][n] = __builtin_amdgcn_mfma_f32_16x16x32_f16(al[m], bh[n], accB[m][n], 0,0,0);
        }
    }
    __syncthreads();
  }
  int r0 = (lane >> 4) << 2, c0 = lane & 15;
  #pragma unroll
  for (int m=0;m<4;m++){
    int grow0 = bm*128 + wr*64 + m*16 + r0;
    #pragma unroll
    for (int n=0;n<4;n++){
      int gcol = bn*128 + wc*64 + n*16 + c0;
      #pragma unroll
      for (int j=0;j<4;j++){
        float v = accA[m][n][j] + accB[m][n][j] * (1.f/4096.f);
        int grow = grow0 + j;
        unsigned short hi, lo; split2(v, hi, lo);
        Ch[(size_t)grow*N + gcol] = hi;
        Cl[(size_t)grow*N + gcol] = lo;
      }
    }
  }
}

// ---------------- O-proj GEMM (split-f16 3-pass, pre-split B) ----------------
// R20: reverted to the plain R18 grid (32,16) — R19's chunked remap was in the
// regressed bundle and is not evidence-backed.
__global__ __launch_bounds__(256,2) void k_gemm_o(
    const unsigned short* __restrict__ Ahi, const unsigned short* __restrict__ Alo,
    const unsigned short* __restrict__ Bhi, const unsigned short* __restrict__ Blo,
    float* __restrict__ C1)
{
  const int Kd = HDIM, N = 2048;
  int bm = blockIdx.x, bn = blockIdx.y;

  __shared__ unsigned short As[2][8192];
  __shared__ unsigned short Bs[2][8192];

  int tid = threadIdx.x, lane = tid & 63, w = tid >> 6;
  int wr = w >> 1, wc = w & 1;

  size_t arow_g[4], brow_g[4];
  int lb_[4];
  #pragma unroll
  for (int i=0;i<4;i++){
    int ob = w*4096 + i*1024 + lane*16;
    int row = ob >> 7;
    int colB = ob & 127;
    int scolB = colB ^ ((row & 7) << 4);
    arow_g[i] = (size_t)(bm*128 + row) * Kd + (scolB >> 1);
    brow_g[i] = (size_t)(bn*128 + row) * Kd + (scolB >> 1);
    lb_[i] = (w*4096 + i*1024) >> 1;
  }

  f32x4 accA[4][4] = {};
  f32x4 accB[4][4] = {};

  for (int kt = 0; kt < Kd/64; kt++){
    #pragma unroll
    for (int i=0;i<4;i++){
      gl_lds16(Ahi + arow_g[i] + kt*64, (void*)&As[0][lb_[i]]);
      gl_lds16(Alo + arow_g[i] + kt*64, (void*)&As[1][lb_[i]]);
      gl_lds16(Bhi + brow_g[i] + kt*64, (void*)&Bs[0][lb_[i]]);
      gl_lds16(Blo + brow_g[i] + kt*64, (void*)&Bs[1][lb_[i]]);
    }
    __syncthreads();
    #pragma unroll
    for (int kk=0; kk<2; kk++){
      f16x8 ah[4], al[4], bh[4], bl[4];
      #pragma unroll
      for (int m=0;m<4;m++){
        int row = wr*64 + m*16 + (lane & 15);
        int ci = (kk*32 + ((lane>>4)<<3)) ^ ((row & 7) << 3);
        ah[m] = *(const f16x8*)&As[0][row*64 + ci];
        al[m] = *(const f16x8*)&As[1][row*64 + ci];
      }
      #pragma unroll
      for (int n=0;n<4;n++){
        int row = wc*64 + n*16 + (lane & 15);
        int ci = (kk*32 + ((lane>>4)<<3)) ^ ((row & 7) << 3);
        bh[n] = *(const f16x8*)&Bs[0][row*64 + ci];
        bl[n] = *(const f16x8*)&Bs[1][row*64 + ci];
      }
      #pragma unroll
      for (int m=0;m<4;m++)
        #pragma unroll
        for (int n=0;n<4;n++){
          accA[m][n] = __builtin_amdgcn_mfma_f32_16x16x32_f16(ah[m], bh[n], accA[m][n], 0,0,0);
          accB[m][n] = __builtin_amdgcn_mfma_f32_16x16x32_f16(ah[m], bl[n], accB[m][n], 0,0,0);
          accB[m][n] = __builtin_amdgcn_mfma_f32_16x16x32_f16(al[m], bh[n], accB[m][n], 0,0,0);
        }
    }
    __syncthreads();
  }
  int r0 = (lane >> 4) << 2, c0 = lane & 15;
  #pragma unroll
  for (int m=0;m<4;m++){
    int grow0 = bm*128 + wr*64 + m*16 + r0;
    #pragma unroll
    for (int n=0;n<4;n++){
      int gcol = bn*128 + wc*64 + n*16 + c0;
      #pragma unroll
      for (int j=0;j<4;j++){
        float v = accA[m][n][j] + accB[m][n][j] * (1.f/4096.f);
        int grow = grow0 + j;
        C1[(size_t)grow*N + gcol] += v;
      }
    }
  }
}

// ---------------- MoE down GEMM (1-pass f16, dense A, per-slot store) ----------------
// R18: grid (bn, e, bm) — bm-blocks sharing a B-panel land on one XCD (T1).
__global__ __launch_bounds__(256,2) void k_gemm_down(
    const unsigned short* __restrict__ Aact,
    const float* __restrict__ Bsrc,
    float* __restrict__ yp,
    const int* __restrict__ erow, const int* __restrict__ counts)
{
  const int Kd = FF, N = HDIM;
  int bn = blockIdx.x, e = blockIdx.y, bm = blockIdx.z;
  int cnt = counts[e]; if (bm*128 >= cnt) return;
  const float* Bp = Bsrc + (size_t)e*Kd*N;
  const unsigned short* Abase = Aact + (size_t)e*CCAP*Kd;

  __shared__ unsigned short As[8192];
  __shared__ unsigned short Bs[8192];

  int tid = threadIdx.x, lane = tid & 63, w = tid >> 6;
  int wr = w >> 1, wc = w & 1;

  size_t arow_g[4];
  int lb_[4];
  #pragma unroll
  for (int i=0;i<4;i++){
    int ob = w*4096 + i*1024 + lane*16;
    int row = ob >> 7;
    int colB = ob & 127;
    int scolB = colB ^ ((row & 7) << 4);
    int grow = bm*128 + row;
    arow_g[i] = (size_t)grow * Kd + (scolB >> 1);
    lb_[i] = (w*4096 + i*1024) >> 1;
  }

  f32x4 accA[4][4] = {};

  int nK = Kd >> 6;
  for (int kt = 0; kt < nK; kt++){
    #pragma unroll
    for (int i=0;i<4;i++)
      gl_lds16(Abase + arow_g[i] + kt*64, (void*)&As[lb_[i]]);
    #pragma unroll
    for (int it=0; it<2; it++){
      int b2 = tid + it*256;
      int k0 = (b2 >> 5) << 2;
      int n0 = (b2 & 31) << 2;
      const float* bp = Bp + (size_t)(kt*64 + k0)*N + bn*128 + n0;
      float4 f0 = *(const float4*)bp;
      float4 f1 = *(const float4*)(bp + (size_t)N);
      float4 f2 = *(const float4*)(bp + 2*(size_t)N);
      float4 f3 = *(const float4*)(bp + 3*(size_t)N);
      #define DO_COL(J, CX) { \
        int rown = n0 + J; \
        int idx = rown*64 + (k0 ^ bswz(rown)); \
        u16x4 ph; ph.x=f2h(f0.CX); ph.y=f2h(f1.CX); ph.z=f2h(f2.CX); ph.w=f2h(f3.CX); \
        *(u16x4*)&Bs[idx] = ph; }
      DO_COL(0, x) DO_COL(1, y) DO_COL(2, z) DO_COL(3, w)
      #undef DO_COL
    }
    __syncthreads();
    #pragma unroll
    for (int kk=0; kk<2; kk++){
      f16x8 ah[4], bh[4];
      #pragma unroll
      for (int m=0;m<4;m++){
        int row = wr*64 + m*16 + (lane & 15);
        int ci = (kk*32 + ((lane>>4)<<3)) ^ ((row & 7) << 3);
        ah[m] = *(const f16x8*)&As[row*64 + ci];
      }
      #pragma unroll
      for (int n=0;n<4;n++){
        int row = wc*64 + n*16 + (lane & 15);
        int ci = (kk*32 + ((lane>>4)<<3)) ^ bswz(row);
        bh[n] = *(const f16x8*)&Bs[row*64 + ci];
      }
      #pragma unroll
      for (int m=0;m<4;m++)
        #pragma unroll
        for (int n=0;n<4;n++)
          accA[m][n] = __builtin_amdgcn_mfma_f32_16x16x32_f16(ah[m], bh[n], accA[m][n], 0,0,0);
    }
    __syncthreads();
  }
  int r0 = (lane >> 4) << 2, c0 = lane & 15;
  #pragma unroll
  for (int m=0;m<4;m++){
    int grow0 = bm*128 + wr*64 + m*16 + r0;
    #pragma unroll
    for (int n=0;n<4;n++){
      int gcol = bn*128 + wc*64 + n*16 + c0;
      #pragma unroll
      for (int j=0;j<4;j++){
        int grow = grow0 + j;
        if (grow < cnt){
          int p = erow[e*CCAP + grow];
          yp[(size_t)p*N + gcol] = accA[m][n][j];
        }
      }
    }
  }
}

// ---------------- R16: gu GEMM with fused SiLU ----------------
// R18: grid (bn, e, bm) — bm-blocks sharing a B-panel land on one XCD (T1).
__global__ __launch_bounds__(256,2) void k_gemm_gu(
    const unsigned short* __restrict__ Ahi,
    const float* __restrict__ Bsrc,
    unsigned short* __restrict__ act,
    const int* __restrict__ erow, const int* __restrict__ counts)
{
  const int Kd = HDIM, N = 1536;
  int bn = blockIdx.x, e = blockIdx.y, bm = blockIdx.z;
  int cnt = counts[e]; if (bm*128 >= cnt) return;
  const float* Bp = Bsrc + (size_t)e*Kd*N;

  __shared__ unsigned short As [8192];
  __shared__ unsigned short BsG[8192];
  __shared__ unsigned short BsU[8192];

  int tid = threadIdx.x, lane = tid & 63, w = tid >> 6;
  int wr = w >> 1, wc = w & 1;

  size_t arow_g[4];
  int lb_[4];
  #pragma unroll
  for (int i=0;i<4;i++){
    int ob = w*4096 + i*1024 + lane*16;
    int row = ob >> 7;
    int colB = ob & 127;
    int scolB = colB ^ ((row & 7) << 4);
    int grow = erow[e*CCAP + bm*128 + row] >> 1;
    arow_g[i] = (size_t)grow * Kd + (scolB >> 1);
    lb_[i] = (w*4096 + i*1024) >> 1;
  }

  f32x4 accG[4][4] = {};
  f32x4 accU[4][4] = {};

  for (int kt = 0; kt < Kd/64; kt++){
    #pragma unroll
    for (int i=0;i<4;i++)
      gl_lds16(Ahi + arow_g[i] + kt*64, (void*)&As[lb_[i]]);
    #pragma unroll
    for (int it=0; it<2; it++){
      int b2 = tid + it*256;
      int k0 = (b2 >> 5) << 2;
      int n0 = (b2 & 31) << 2;
      const float* bpg = Bp + (size_t)(kt*64 + k0)*N + bn*128 + n0;
      const float* bpu = bpg + 768;
      float4 g0 = *(const float4*)bpg;
      float4 g1 = *(const float4*)(bpg + (size_t)N);
      float4 g2 = *(const float4*)(bpg + 2*(size_t)N);
      float4 g3 = *(const float4*)(bpg + 3*(size_t)N);
      float4 u0 = *(const float4*)bpu;
      float4 u1 = *(const float4*)(bpu + (size_t)N);
      float4 u2 = *(const float4*)(bpu + 2*(size_t)N);
      float4 u3 = *(const float4*)(bpu + 3*(size_t)N);
      #define DO_COL2(J, CX) { \
        int rown = n0 + J; \
        int idx = rown*64 + (k0 ^ bswz(rown)); \
        u16x4 pg; pg.x=f2h(g0.CX); pg.y=f2h(g1.CX); pg.z=f2h(g2.CX); pg.w=f2h(g3.CX); \
        *(u16x4*)&BsG[idx] = pg; \
        u16x4 pu; pu.x=f2h(u0.CX); pu.y=f2h(u1.CX); pu.z=f2h(u2.CX); pu.w=f2h(u3.CX); \
        *(u16x4*)&BsU[idx] = pu; }
      DO_COL2(0, x) DO_COL2(1, y) DO_COL2(2, z) DO_COL2(3, w)
      #undef DO_COL2
    }
    __syncthreads();
    #pragma unroll
    for (int kk=0; kk<2; kk++){
      f16x8 ah[4], bg[4], bu[4];
      #pragma unroll
      for (int m=0;m<4;m++){
        int row = wr*64 + m*16 + (lane & 15);
        int ci = (kk*32 + ((lane>>4)<<3)) ^ ((row & 7) << 3);
        ah[m] = *(const f16x8*)&As[row*64 + ci];
      }
      #pragma unroll
      for (int n=0;n<4;n++){
        int row = wc*64 + n*16 + (lane & 15);
        int ci = (kk*32 + ((lane>>4)<<3)) ^ bswz(row);
        bg[n] = *(const f16x8*)&BsG[row*64 + ci];
        bu[n] = *(const f16x8*)&BsU[row*64 + ci];
      }
      #pragma unroll
      for (int m=0;m<4;m++)
        #pragma unroll
        for (int n=0;n<4;n++){
          accG[m][n] = __builtin_amdgcn_mfma_f32_16x16x32_f16(ah[m], bg[n], accG[m][n], 0,0,0);
          accU[m][n] = __builtin_amdgcn_mfma_f32_16x16x32_f16(ah[m], bu[n], accU[m][n], 0,0,0);
        }
    }
    __syncthreads();
  }
  int r0 = (lane >> 4) << 2, c0 = lane & 15;
  #pragma unroll
  for (int m=0;m<4;m++){
    int grow0 = bm*128 + wr*64 + m*16 + r0;
    #pragma unroll
    for (int n=0;n<4;n++){
      int gcol = bn*128 + wc*64 + n*16 + c0;
      #pragma unroll
      for (int j=0;j<4;j++){
        int grow = grow0 + j;
        unsigned short g16 = f2h(accG[m][n][j]);
        unsigned short u16_ = f2h(accU[m][n][j]);
        float gf = h2f(g16), uf = h2f(u16_);
        float s = gf / (1.f + __expf(-gf));
        act[((size_t)e*CCAP + grow)*FF + gcol] = f2h(s * uf);
      }
    }
  }
}

// ---------------- flash attention (split-f16 3-pass, causal, GQA) ----------------
// R15 kernel verbatim (247 us best measured). T15 phase pipeline: QK^T of tile
// t+1 computed inside tile t's softmax window (dbuf, stage distance 2);
// setprio around MFMA clusters.
__global__ __launch_bounds__(512,2) void k_attn(
    const unsigned short* __restrict__ qh, const unsigned short* __restrict__ ql,
    const unsigned short* __restrict__ kh, const unsigned short* __restrict__ kl,
    const unsigned short* __restrict__ vh, const unsigned short* __restrict__ vl,
    unsigned short* __restrict__ oh, unsigned short* __restrict__ ol)
{
  int h = blockIdx.y, b = blockIdx.z;
  int qt = b ? (15 - blockIdx.x) : blockIdx.x;    // load-balance pairing
  int hkv = h >> 2;
  int tid = threadIdx.x, lane = tid & 63, w = tid >> 6;   // 8 waves

  __shared__ unsigned short Ks[2][2][8192];  // [buf][plane][kv64 x d128], XOR-16B swizzled
  __shared__ unsigned short Vs[2][2][8192];  // [buf][plane][d128 x kv64] transposed, XOR-8 swizzled
  __shared__ unsigned short Ps[8][2][1024];  // per-wave [r16 x kv64]

  int qrow = qt*128 + w*16 + (lane & 15);
  size_t qoff = ((size_t)(b*SEQ + qrow)*NHQ + h)*DH + ((lane>>4)<<3);
  f16x8 qfh[4], qfl[4];
  #pragma unroll
  for (int kk=0; kk<4; kk++){
    qfh[kk] = *(const f16x8*)(qh + qoff + kk*32);
    qfl[kk] = *(const f16x8*)(ql + qoff + kk*32);
  }

  const size_t SROW = (size_t)NKVH*DH;
  size_t kvbase = (size_t)b*SEQ*SROW + (size_t)hkv*DH;
  int kob[2]; size_t koff[2];
  #pragma unroll
  for (int i=0;i<2;i++){
    int ob = i*8192 + tid*16;
    int row = ob >> 8;
    int scol = (ob & 255) ^ ((row & 7) << 4);
    kob[i] = ob;
    koff[i] = (size_t)row*SROW + (scol >> 1);
  }
  int vkvp = (tid & 31) * 2;
  int vd0  = ((tid >> 5) & 15) * 8;
  size_t voff0 = (size_t)vkvp*SROW + vd0;
  size_t voff1 = voff0 + SROW;

  u16x8 pkh[2], pkl[2];
  u16x8 pvh[2], pvl[2];

  #define STAGE_LOAD(KVT) { \
    size_t tb = kvbase + (size_t)(KVT)*64*SROW; \
    _Pragma("unroll") \
    for (int i=0;i<2;i++){ pkh[i] = *(const u16x8*)(kh + tb + koff[i]); \
                           pkl[i] = *(const u16x8*)(kl + tb + koff[i]); } \
    pvh[0] = *(const u16x8*)(vh + tb + voff0); \
    pvh[1] = *(const u16x8*)(vh + tb + voff1); \
    pvl[0] = *(const u16x8*)(vl + tb + voff0); \
    pvl[1] = *(const u16x8*)(vl + tb + voff1); }

  #define STAGE_WRITE(BUF) { \
    _Pragma("unroll") \
    for (int i=0;i<2;i++){ \
      *(u16x8*)((char*)&Ks[BUF][0][0] + kob[i]) = pkh[i]; \
      *(u16x8*)((char*)&Ks[BUF][1][0] + kob[i]) = pkl[i]; } \
    _Pragma("unroll") \
    for (int jj=0;jj<8;jj++){ \
      int row = vd0 + jj; \
      int idx = row*64 + (vkvp ^ ((jj & 7) << 3)); \
      *(unsigned int*)&Vs[BUF][0][idx] = (unsigned int)pvh[0][jj] | ((unsigned int)pvh[1][jj] << 16); \
      *(unsigned int*)&Vs[BUF][1][idx] = (unsigned int)pvl[0][jj] | ((unsigned int)pvl[1][jj] << 16); } }

  // scores for tile KVT from buffer BUF -> p[4][4], mx[4] (combine+mask+lane max)
  #define QKT(KVT, BUF) { \
    f32x4 saA[4] = {}; \
    f32x4 saB[4] = {}; \
    __builtin_amdgcn_s_setprio(1); \
    _Pragma("unroll") \
    for (int kk=0; kk<4; kk++){ \
      _Pragma("unroll") \
      for (int n=0;n<4;n++){ \
        int row = n*16 + (lane & 15); \
        int ci = (kk*32 + ((lane>>4)<<3)) ^ ((row & 7) << 3); \
        f16x8 kfh = *(const f16x8*)&Ks[BUF][0][row*128 + ci]; \
        f16x8 kfl = *(const f16x8*)&Ks[BUF][1][row*128 + ci]; \
        saA[n] = __builtin_amdgcn_mfma_f32_16x16x32_f16(qfh[kk], kfh, saA[n], 0,0,0); \
        saB[n] = __builtin_amdgcn_mfma_f32_16x16x32_f16(qfh[kk], kfl, saB[n], 0,0,0); \
        saB[n] = __builtin_amdgcn_mfma_f32_16x16x32_f16(qfl[kk], kfh, saB[n], 0,0,0); } } \
    __builtin_amdgcn_s_setprio(0); \
    _Pragma("unroll") \
    for (int j=0;j<4;j++) mx[j] = -1e30f; \
    int qg = qt*128 + w*16 + ((lane>>4)<<2); \
    _Pragma("unroll") \
    for (int n=0;n<4;n++){ \
      int kvcol = (KVT)*64 + n*16 + (lane & 15); \
      _Pragma("unroll") \
      for (int j=0;j<4;j++){ \
        float sv = saA[n][j] + saB[n][j]*(1.f/4096.f); \
        if (kvcol > qg + j) sv = -1e30f; \
        p[n][j] = sv; \
        mx[j] = fmaxf(mx[j], sv); } } }

  // online-softmax update; consumes p/mx into Ps[w] + rescales oacc
  #define SOFTMAX() { \
    _Pragma("unroll") \
    for (int sh=1; sh<16; sh<<=1) \
      _Pragma("unroll") \
      for (int j=0;j<4;j++) mx[j] = fmaxf(mx[j], __shfl_xor(mx[j], sh)); \
    float rs[4], sum[4]; \
    _Pragma("unroll") \
    for (int j=0;j<4;j++){ \
      float mn = fmaxf(m_[j], mx[j]); \
      rs[j] = __expf(m_[j] - mn); \
      float sm = 0.f; \
      _Pragma("unroll") \
      for (int n=0;n<4;n++){ float pe = __expf(p[n][j] - mn); p[n][j] = pe; sm += pe; } \
      sum[j] = sm; \
      m_[j] = mn; } \
    _Pragma("unroll") \
    for (int sh=1; sh<16; sh<<=1) \
      _Pragma("unroll") \
      for (int j=0;j<4;j++) sum[j] += __shfl_xor(sum[j], sh); \
    _Pragma("unroll") \
    for (int j=0;j<4;j++) l_[j] = l_[j]*rs[j] + sum[j]; \
    _Pragma("unroll") \
    for (int d=0;d<8;d++) \
      _Pragma("unroll") \
      for (int j=0;j<4;j++){ oaccA[d][j] *= rs[j]; oaccB[d][j] *= rs[j]; } \
    _Pragma("unroll") \
    for (int n=0;n<4;n++) \
      _Pragma("unroll") \
      for (int j=0;j<4;j++){ \
        int r = ((lane>>4)<<2) + j; \
        int c = n*16 + (lane & 15); \
        int idx = r*64 + (c ^ ((r & 7) << 3)); \
        unsigned short ph, pl2; split2(p[n][j], ph, pl2); \
        Ps[w][0][idx] = ph; \
        Ps[w][1][idx] = pl2; } }

  #define PVOP(BUF) { \
    __builtin_amdgcn_s_setprio(1); \
    _Pragma("unroll") \
    for (int kk=0; kk<2; kk++){ \
      int prow = lane & 15; \
      int pidx = prow*64 + ((kk*32 + ((lane>>4)<<3)) ^ ((prow & 7) << 3)); \
      f16x8 pah = *(const f16x8*)&Ps[w][0][pidx]; \
      f16x8 pal = *(const f16x8*)&Ps[w][1][pidx]; \
      _Pragma("unroll") \
      for (int d=0;d<8;d++){ \
        int row = d*16 + (lane & 15); \
        int ci = (kk*32 + ((lane>>4)<<3)) ^ ((row & 7) << 3); \
        f16x8 vfh = *(const f16x8*)&Vs[BUF][0][row*64 + ci]; \
        f16x8 vfl = *(const f16x8*)&Vs[BUF][1][row*64 + ci]; \
        oaccA[d] = __builtin_amdgcn_mfma_f32_16x16x32_f16(pah, vfh, oaccA[d], 0,0,0); \
        oaccB[d] = __builtin_amdgcn_mfma_f32_16x16x32_f16(pah, vfl, oaccB[d], 0,0,0); \
        oaccB[d] = __builtin_amdgcn_mfma_f32_16x16x32_f16(pal, vfh, oaccB[d], 0,0,0); } } \
    __builtin_amdgcn_s_setprio(0); }

  float m_[4], l_[4];
  f32x4 oaccA[8] = {};
  f32x4 oaccB[8] = {};
  #pragma unroll
  for (int j=0;j<4;j++){ m_[j] = -1e30f; l_[j] = 0.f; }

  int nkt = 2*qt + 2;                 // >= 2 always
  STAGE_LOAD(0); STAGE_WRITE(0);
  STAGE_LOAD(1); STAGE_WRITE(1);
  __syncthreads();

  float p[4][4], mx[4];
  QKT(0, 0);                          // tile 0 is active for every wave

  for (int kvt = 0; kvt < nkt; kvt++){
    int cur = kvt & 1, nxt = cur ^ 1;
    if (kvt+2 < nkt) STAGE_LOAD(kvt+2);

    bool active = (kvt*64 <= qt*128 + w*16 + 15);
    bool actn   = (kvt+1 < nkt) && ((kvt+1)*64 <= qt*128 + w*16 + 15);
    if (actn){
      // one straight-line region: softmax(t) VALU overlaps QKT(t+1) MFMA
      SOFTMAX();
      QKT(kvt+1, nxt);
      PVOP(cur);
    } else if (active){
      SOFTMAX();
      PVOP(cur);
    }
    __syncthreads();                  // all reads of buf[cur] (V of tile t) done
    if (kvt+2 < nkt) STAGE_WRITE(cur);
    __syncthreads();                  // publish tile t+2 for iter t+1's QKT
  }
  #undef STAGE_LOAD
  #undef STAGE_WRITE
  #undef QKT
  #undef SOFTMAX
  #undef PVOP

  #pragma unroll
  for (int j=0;j<4;j++) l_[j] = 1.f / l_[j];
  #pragma unroll
  for (int d=0;d<8;d++)
    #pragma unroll
    for (int j=0;j<4;j++){
      int qr = qt*128 + w*16 + ((lane>>4)<<2) + j;
      size_t off = ((size_t)(b*SEQ + qr)*NHQ + h)*DH + d*16 + (lane & 15);
      float v = (oaccA[d][j] + oaccB[d][j]*(1.f/4096.f)) * l_[j];
      unsigned short hi, lo; split2(v, hi, lo);
      oh[off] = hi; ol[off] = lo;
    }
}

// ---------------- fused post-attn RMSNorm -> x2  +  gate top-2 ----------------
// R20: reverted to the exact R18 LDS-tree reduction — R19's shuffle butterfly
// was in the regressed bundle.
__global__ __launch_bounds__(256) void k_ln2gate(
    const float* __restrict__ resid, const float* __restrict__ wln,
    const float* __restrict__ gw,
    unsigned short* __restrict__ x2, float* __restrict__ topw, int* __restrict__ topid)
{
  int t = blockIdx.x, tid = threadIdx.x;
  size_t off = (size_t)t * HDIM;
  float4 s0 = ((const float4*)(resid+off))[tid];
  float4 s1 = ((const float4*)(resid+off))[tid+256];
  float ssq = s0.x*s0.x+s0.y*s0.y+s0.z*s0.z+s0.w*s0.w
            + s1.x*s1.x+s1.y*s1.y+s1.z*s1.z+s1.w*s1.w;
  #pragma unroll
  for (int sh=1; sh<64; sh<<=1) ssq += __shfl_xor(ssq, sh);
  __shared__ float red[4];
  if ((tid & 63) == 0) red[tid>>6] = ssq;
  __syncthreads();
  float tot = red[0]+red[1]+red[2]+red[3];
  float r = 1.f / sqrtf(tot * (1.f/HDIM) + EPSF);
  float4 w0 = ((const float4*)wln)[tid];
  float4 w1 = ((const float4*)wln)[tid+256];
  float xs[8] = { s0.x*r*w0.x, s0.y*r*w0.y, s0.z*r*w0.z, s0.w*r*w0.w,
                  s1.x*r*w1.x, s1.y*r*w1.y, s1.z*r*w1.z, s1.w*r*w1.w };
  u16x4 hv;
  hv.x = f2h(xs[0]); hv.y = f2h(xs[1]); hv.z = f2h(xs[2]); hv.w = f2h(xs[3]);
  ((u16x4*)(x2+off))[tid] = hv;
  hv.x = f2h(xs[4]); hv.y = f2h(xs[5]); hv.z = f2h(xs[6]); hv.w = f2h(xs[7]);
  ((u16x4*)(x2+off))[tid+256] = hv;

  double acc[16];
  #pragma unroll
  for (int e2=0;e2<16;e2++) acc[e2] = 0.0;
  #pragma unroll
  for (int i=0;i<8;i++){
    int hidx = (i<4) ? (tid*4 + i) : (1024 + tid*4 + (i-4));
    const float4* g4 = (const float4*)(gw + (size_t)hidx*NE);
    float4 ga=g4[0], gb=g4[1], gc=g4[2], gd=g4[3];
    double xx = (double)xs[i];
    acc[0]+=xx*ga.x;  acc[1]+=xx*ga.y;  acc[2]+=xx*ga.z;  acc[3]+=xx*ga.w;
    acc[4]+=xx*gb.x;  acc[5]+=xx*gb.y;  acc[6]+=xx*gb.z;  acc[7]+=xx*gb.w;
    acc[8]+=xx*gc.x;  acc[9]+=xx*gc.y;  acc[10]+=xx*gc.z; acc[11]+=xx*gc.w;
    acc[12]+=xx*gd.x; acc[13]+=xx*gd.y; acc[14]+=xx*gd.z; acc[15]+=xx*gd.w;
  }
  __shared__ double red2[256][16];
  #pragma unroll
  for (int e2=0;e2<16;e2++) red2[tid][e2] = acc[e2];
  __syncthreads();
  for (int s=128; s>=1; s>>=1){
    if (tid < s){
      #pragma unroll
      for (int e2=0;e2<16;e2++) red2[tid][e2] += red2[tid+s][e2];
    }
    __syncthreads();
  }
  if (tid == 0){
    float l[16];
    #pragma unroll
    for (int e2=0;e2<16;e2++) l[e2] = (float)red2[0][e2];
    int i0 = 0;
    #pragma unroll
    for (int e2=1;e2<16;e2++) if (l[e2] > l[i0]) i0 = e2;
    int i1 = (i0 == 0) ? 1 : 0;
    #pragma unroll
    for (int e2=0;e2<16;e2++) if (e2 != i0 && l[e2] > l[i1]) i1 = e2;
    float w0t = 1.f / (1.f + expf(l[i1] - l[i0]));
    topw[t*2+0] = w0t; topw[t*2+1] = 1.f - w0t;
    topid[t*2+0] = i0; topid[t*2+1] = i1;
  }
}

// ---------------- routing: exact stable counting sort ----------------
__global__ __launch_bounds__(256) void k_route(
    int* __restrict__ topid, int* __restrict__ erow, int* __restrict__ counts)
{
  int tid = threadIdx.x;
  __shared__ unsigned short cnt[256][16];
  for (int i = tid; i < NE*CCAP; i += 256) erow[i] = 0;
  int loc[16];
  #pragma unroll
  for (int e2=0;e2<16;e2++) loc[e2] = 0;
  int myid[32];
  for (int i=0;i<32;i++){
    int e2 = topid[tid*32 + i];
    myid[i] = e2;
    loc[e2]++;
  }
  #pragma unroll
  for (int e2=0;e2<16;e2++) cnt[tid][e2] = (unsigned short)loc[e2];
  __syncthreads();
  if (tid < 16){
    int run = 0;
    for (int i=0;i<256;i++){ int c = cnt[i][tid]; cnt[i][tid] = (unsigned short)run; run += c; }
    counts[tid] = run > CCAP ? CCAP : run;
  }
  __syncthreads();
  #pragma unroll
  for (int e2=0;e2<16;e2++) loc[e2] = cnt[tid][e2];
  for (int i=0;i<32;i++){
    int e2 = myid[i];
    int pos = loc[e2]++;
    int p = tid*32 + i;
    int ok = (pos < CCAP);
    if (ok) erow[e2*CCAP + pos] = p;
    topid[p] = ok;                      // recycle topid as slot-valid flag
  }
}

// ---------------- R6: gather per-slot down rows -> weighted token sum ----------------
__global__ __launch_bounds__(256) void k_gather(
    const float* __restrict__ yp, const int* __restrict__ valid,
    const float* __restrict__ topw, float* __restrict__ y)
{
  int t = blockIdx.x, tid = threadIdx.x;
  int v0 = valid[t*2+0], v1 = valid[t*2+1];
  float w0 = topw[t*2+0], w1 = topw[t*2+1];
  size_t o = (size_t)t*2*HDIM;
  const float4* r0 = (const float4*)(yp + o);
  const float4* r1 = (const float4*)(yp + o + HDIM);
  float4* yo = (float4*)(y + (size_t)t*HDIM);
  #pragma unroll
  for (int i=0;i<2;i++){
    int ix = tid + i*256;
    float4 a = r0[ix];
    float4 b = r1[ix];
    float4 out;
    float a0 = v0 ? w0 : 0.f;
    float b0 = v1 ? w1 : 0.f;
    out.x = (v0 ? a.x*a0 : 0.f) + (v1 ? b.x*b0 : 0.f);
    out.y = (v0 ? a.y*a0 : 0.f) + (v1 ? b.y*b0 : 0.f);
    out.z = (v0 ? a.z*a0 : 0.f) + (v1 ? b.z*b0 : 0.f);
    out.w = (v0 ? a.w*a0 : 0.f) + (v1 ? b.w*b0 : 0.f);
    yo[ix] = out;
  }
}

extern "C" void kernel_launch(void* const* d_in, const int* in_sizes, int n_in,
                              void* d_out, int out_size, void* d_ws, size_t ws_size,
                              hipStream_t stream)
{
  (void)in_sizes; (void)n_in; (void)out_size; (void)ws_size;
  const int*   positions = (const int*)  d_in[0];
  const float* hs        = (const float*)d_in[1];
  const float* res       = (const float*)d_in[2];
  const float* w_in_ln   = (const float*)d_in[3];
  const float* wq        = (const float*)d_in[4];
  const float* wk        = (const float*)d_in[5];
  const float* wv        = (const float*)d_in[6];
  const float* wo        = (const float*)d_in[7];
  const float* q_norm_w  = (const float*)d_in[8];
  const float* k_norm_w  = (const float*)d_in[9];
  const float* w_post_ln = (const float*)d_in[10];
  const float* gate_w    = (const float*)d_in[11];
  const float* w_gate_up = (const float*)d_in[12];
  const float* w_down    = (const float*)d_in[13];

  float* y      = (float*)d_out;
  float* resid2 = y + (size_t)T_TOK*HDIM;

  char* ws = (char*)d_ws;
  unsigned short* hhi = (unsigned short*)(ws + 0);
  unsigned short* hlo = (unsigned short*)(ws + 16777216);
  unsigned short* qh  = (unsigned short*)(ws + 33554432);
  unsigned short* ql  = (unsigned short*)(ws + 50331648);
  unsigned short* kh  = (unsigned short*)(ws + 67108864);
  unsigned short* kl  = (unsigned short*)(ws + 71303168);
  unsigned short* vh  = (unsigned short*)(ws + 75497472);
  unsigned short* vl  = (unsigned short*)(ws + 79691776);
  unsigned short* oh  = (unsigned short*)(ws + 83886080);
  unsigned short* ol  = (unsigned short*)(ws + 100663296);
  unsigned short* x2  = (unsigned short*)(ws + 117440512);
  // R13 weight-plane overlays (time-disjoint with oh/ol and x2):
  unsigned short* qkvwh = (unsigned short*)(ws + 83886080);  // 12.58 MB
  unsigned short* qkvwl = (unsigned short*)(ws + 96468992);  // 12.58 MB
  unsigned short* wowh  = (unsigned short*)(ws + 117440512); // 8.39 MB
  unsigned short* wowl  = (unsigned short*)(ws + 125829120); // 8.39 MB
  // MoE-phase overlays (attention-phase buffers are dead by then):
  unsigned short* act = (unsigned short*)(ws + 67108864);    // [gemm_gu, gemm_down]
  float*          yp  = (float*)         (ws + 0);           // [gemm_down, gather]
  float* cstab        = (float*)(ws + 134217728);
  float* topw         = (float*)(ws + 135266304);
  int*   topid        = (int*)  (ws + 135299072);
  int*   counts       = (int*)  (ws + 135331840);
  int*   erow         = (int*)  (ws + 135332096);

  k_addnorm<<<T_TOK, 256, 0, stream>>>(hs, res, w_in_ln, resid2, hhi, hlo);
  k_cstab<<<(SEQ*64 + 255)/256, 256, 0, stream>>>(positions, cstab);
  // one-time weight split+transpose (R13; merged QKV launch kept from R19)
  k_wsplit3<<<dim3(32, 48), 256, 0, stream>>>(wq, wk, wv, qkvwh, qkvwl);
  k_wsplit<<<dim3(32, 32), 256, 0, stream>>>(wo, HDIM, 2048, wowh, wowl);
  k_gemm_qkv<<<dim3(32,24,1), 256, 0, stream>>>(hhi, hlo, qkvwh, qkvwl, qh, ql, kh, kl, vh, vl);
  k_normrope<<<dim3(T_TOK, 5), 256, 0, stream>>>(qh, ql, kh, kl, q_norm_w, k_norm_w, cstab);
  k_attn<<<dim3(16, 16, 2), 512, 0, stream>>>(qh, ql, kh, kl, vh, vl, oh, ol);
  k_gemm_o<<<dim3(32,16,1), 256, 0, stream>>>(oh, ol, wowh, wowl, resid2);
  k_ln2gate<<<T_TOK, 256, 0, stream>>>(resid2, w_post_ln, gate_w, x2, topw, topid);
  k_route<<<1, 256, 0, stream>>>(topid, erow, counts);
  k_gemm_gu<<<dim3(6,16,8), 256, 0, stream>>>(x2, w_gate_up, act, erow, counts);
  k_gemm_down<<<dim3(16,16,8), 256, 0, stream>>>(act, w_down, yp, erow, counts);
  k_gather<<<T_TOK, 256, 0, stream>>>(yp, topid, topw, y);
}